// Round 5
// baseline (502.206 us; speedup 1.0000x reference)
//
#include <hip/hip_runtime.h>
#include <hip/hip_bf16.h>

typedef __bf16 bf16;
typedef __bf16 bf16x4 __attribute__((ext_vector_type(4)));
typedef __bf16 bf16x8 __attribute__((ext_vector_type(8)));
typedef float f32x4 __attribute__((ext_vector_type(4)));

__device__ __forceinline__ float fast_exp2(float x) {
#if __has_builtin(__builtin_amdgcn_exp2f)
    return __builtin_amdgcn_exp2f(x);
#else
    return exp2f(x);
#endif
}

// async global->LDS, 16B per lane. lds base must be wave-uniform; the HW
// writes lds + lane*16; the GLOBAL address is per-lane. (m97 pattern)
__device__ __forceinline__ void gload16(bf16* lds, const bf16* g) {
    __builtin_amdgcn_global_load_lds(
        (const __attribute__((address_space(1))) void*)g,
        (__attribute__((address_space(3))) void*)lds,
        16, 0, 0);
}

// ---------------------------------------------------------------------------
// f32 -> bf16 vectorized cast (8 elems / thread)
// ---------------------------------------------------------------------------
__device__ __forceinline__ bf16x8 cvt8(const float* p) {
    float4 a = *(const float4*)p;
    float4 b = *(const float4*)(p + 4);
    bf16x8 r;
    r[0] = (bf16)a.x; r[1] = (bf16)a.y; r[2] = (bf16)a.z; r[3] = (bf16)a.w;
    r[4] = (bf16)b.x; r[5] = (bf16)b.y; r[6] = (bf16)b.z; r[7] = (bf16)b.w;
    return r;
}

__global__ __launch_bounds__(256) void cvt_bf16(
    const float* __restrict__ in, bf16* __restrict__ out, int n8)
{
    int i = blockIdx.x * 256 + threadIdx.x;
    if (i < n8)
        *(bf16x8*)(out + (size_t)i * 8) = cvt8(in + (size_t)i * 8);
}

// ---------------------------------------------------------------------------
// C[M x N] = A[M x K] * B[N x K]^T   (A,B bf16; f32 accum; TC out)
// m97 structure: 128x128 tile, BK=32, linear LDS [128][32] (64B rows),
// global_load_lds dwordx4 staging (4 issues/thread/K-step), 2-barrier loop,
// 4 waves (2x2), each wave 4x4 of 16x16x32 MFMA.
// EPI==0: plain   EPI==1: softplus(acc + bias_f32[col])
// EPI==2: out = gmul_bf16[row,col] * silu(acc)
// grid.z splits K: block z computes K range [z*K, (z+1)*K), stores to
// C + z*zstride (f32 partials for split-K callers; zstride=0 otherwise).
// ---------------------------------------------------------------------------
template <int EPI, typename TC>
__global__ __launch_bounds__(256, 2) void gemm_bt(
    const bf16* __restrict__ A, int lda,
    const bf16* __restrict__ B, int ldb,
    TC* __restrict__ C, int ldc,
    int K, int Neff, const float* __restrict__ bias,
    const bf16* __restrict__ gmul, size_t zstride)
{
    __shared__ bf16 As[128 * 32];
    __shared__ bf16 Bs[128 * 32];

    const int tid  = threadIdx.x;
    const int lane = tid & 63;
    const int wave = tid >> 6;
    const int quad = lane >> 4;
    const int l16  = lane & 15;
    const int wm   = (wave >> 1) << 6;
    const int wn   = (wave & 1) << 6;
    const int bm   = blockIdx.x << 7;
    const int bn   = blockIdx.y << 7;
    const int kb   = blockIdx.z * K;

    // staging map: wave w covers LDS rows [w*16, +16)
    // lane l -> row +(l>>2), col (l&3)*8   (lds dest = uniform base + l*16B)
    const int srow = (wave << 4) + (lane >> 2);
    const int scol = (lane & 3) << 3;

    const bf16* Ag0 = A + (size_t)(bm + srow) * lda + kb + scol;
    const bf16* Ag1 = Ag0 + (size_t)lda * 64;
    int br0 = bn + srow;      br0 = br0 < Neff ? br0 : Neff - 1;
    int br1 = bn + srow + 64; br1 = br1 < Neff ? br1 : Neff - 1;
    const bf16* Bg0 = B + (size_t)br0 * ldb + kb + scol;
    const bf16* Bg1 = B + (size_t)br1 * ldb + kb + scol;

    bf16* Asd0 = As + wave * 512;           // wave-uniform LDS bases
    bf16* Asd1 = As + wave * 512 + 2048;
    bf16* Bsd0 = Bs + wave * 512;
    bf16* Bsd1 = Bs + wave * 512 + 2048;

    f32x4 acc[4][4] = {};

    for (int k0 = 0; k0 < K; k0 += 32) {
        if (k0) __syncthreads();            // protect LDS from overwrite
        gload16(Asd0, Ag0 + k0);
        gload16(Asd1, Ag1 + k0);
        gload16(Bsd0, Bg0 + k0);
        gload16(Bsd1, Bg1 + k0);
        __syncthreads();                    // drains vmcnt before barrier

        bf16x8 af[4], bfr[4];
#pragma unroll
        for (int i = 0; i < 4; ++i) {
            af[i]  = *(const bf16x8*)(As + (wm + i * 16 + l16) * 32 + quad * 8);
            bfr[i] = *(const bf16x8*)(Bs + (wn + i * 16 + l16) * 32 + quad * 8);
        }
#pragma unroll
        for (int mi = 0; mi < 4; ++mi)
#pragma unroll
            for (int ni = 0; ni < 4; ++ni)
                acc[mi][ni] = __builtin_amdgcn_mfma_f32_16x16x32_bf16(
                    af[mi], bfr[ni], acc[mi][ni], 0, 0, 0);
    }

    TC* Cz = C + (size_t)blockIdx.z * zstride;

    // C/D layout: row = quad*4 + r, col = l16  (m89-verified)
#pragma unroll
    for (int mi = 0; mi < 4; ++mi) {
        const int row = bm + wm + mi * 16 + quad * 4;
#pragma unroll
        for (int ni = 0; ni < 4; ++ni) {
            const int col = bn + wn + ni * 16 + l16;
            if (col < Neff) {
                float bc = (EPI == 1) ? bias[col] : 0.f;
#pragma unroll
                for (int r = 0; r < 4; ++r) {
                    float v = acc[mi][ni][r];
                    if (EPI == 1) {
                        v += bc;
                        v = (v > 15.f) ? v : log1pf(__expf(v));
                    } else if (EPI == 2) {
                        float g = v / (1.f + __expf(-v));   // silu(z)
                        v = (float)gmul[(size_t)(row + r) * ldc + col] * g;
                    }
                    Cz[(size_t)(row + r) * ldc + col] = (TC)v;
                }
            }
        }
    }
}

// ---------------------------------------------------------------------------
// split-K reduce: dbc[i] = bf16(sum_z P[z][i]),  n = 8192*96, 4 splits
// ---------------------------------------------------------------------------
__global__ __launch_bounds__(256) void reduce_dbc(
    const float* __restrict__ P, bf16* __restrict__ dbc)
{
    const size_t i = ((size_t)blockIdx.x * 256 + threadIdx.x) * 4;
    f32x4 s = *(const f32x4*)(P + i);
#pragma unroll
    for (int z = 1; z < 4; ++z) {
        f32x4 p = *(const f32x4*)(P + (size_t)z * 786432 + i);
        s[0] += p[0]; s[1] += p[1]; s[2] += p[2]; s[3] += p[3];
    }
    bf16x4 o;
    o[0] = (bf16)s[0]; o[1] = (bf16)s[1]; o[2] = (bf16)s[2]; o[3] = (bf16)s[3];
    *(bf16x4*)(dbc + i) = o;
}

// ---------------------------------------------------------------------------
// causal depthwise conv (k=4, left pad 3) + bias + SiLU: xh bf16 -> xc bf16
// t-tiled: each thread produces 8 consecutive t for 8 channels.
// ---------------------------------------------------------------------------
__global__ __launch_bounds__(256) void conv_kernel(
    const bf16* __restrict__ xh, const float* __restrict__ cw,
    const float* __restrict__ cb, bf16* __restrict__ xc)
{
    const int t0 = blockIdx.x << 3;          // 0..2040
    const int b  = blockIdx.y;
    const int d  = threadIdx.x * 8;

    float4 wv[8];           // wv[i] = taps 0..3 of channel d+i
#pragma unroll
    for (int i = 0; i < 8; ++i)
        wv[i] = *(const float4*)(cw + (d + i) * 4);

    float4 cb0 = *(const float4*)(cb + d);
    float4 cb1 = *(const float4*)(cb + d + 4);

    float acc[8][8];
#pragma unroll
    for (int k = 0; k < 8; ++k) {
        acc[k][0] = cb0.x; acc[k][1] = cb0.y; acc[k][2] = cb0.z; acc[k][3] = cb0.w;
        acc[k][4] = cb1.x; acc[k][5] = cb1.y; acc[k][6] = cb1.z; acc[k][7] = cb1.w;
    }

    const bf16* base = xh + ((size_t)b * 2048 + t0) * 2048 + d;

#pragma unroll
    for (int r = 0; r < 11; ++r) {
        const int t_in = t0 - 3 + r;
        if (t_in >= 0) {                     // uniform branch
            bf16x8 v = *(const bf16x8*)(base + (size_t)(r - 3) * 2048);
            float vf[8];
#pragma unroll
            for (int i = 0; i < 8; ++i) vf[i] = (float)v[i];
#pragma unroll
            for (int j = 0; j < 4; ++j) {    // tap j multiplies x[t-3+j]
                const int local = r - j;     // output index t0+local
                if (local >= 0 && local < 8) {
#pragma unroll
                    for (int i = 0; i < 8; ++i) {
                        float w = (j == 0) ? wv[i].x : (j == 1) ? wv[i].y
                                : (j == 2) ? wv[i].z : wv[i].w;
                        acc[local][i] += w * vf[i];
                    }
                }
            }
        }
    }

    bf16* ob = xc + ((size_t)b * 2048 + t0) * 2048 + d;
#pragma unroll
    for (int k = 0; k < 8; ++k) {
        bf16x8 o;
#pragma unroll
        for (int i = 0; i < 8; ++i) {
            float s = acc[k][i];
            o[i] = (bf16)(s / (1.f + __expf(-s)));
        }
        *(bf16x8*)(ob + (size_t)k * 2048) = o;
    }
}

// ---------------------------------------------------------------------------
// Chunk-parallel selective scan, NC=16 chunks x TC=128 t.
// thread = (b, c, d); all 16 states n in registers.  Software pipeline in
// groups of 4 t: B/C prefetched 1 group ahead, x/dt 2 groups ahead, with
// __builtin_amdgcn_sched_barrier(0) fences so hipcc cannot sink the
// prefetch loads to their uses (r4 post-mortem: VGPR=60 proved it did).
// Hbuf/Abuf layout: (b, c, d, n).
// ---------------------------------------------------------------------------
__global__ __launch_bounds__(256, 2) void scan_p1(
    const bf16* __restrict__ delta, const bf16* __restrict__ dbc,
    const float* __restrict__ A_raw, const bf16* __restrict__ xc,
    float* __restrict__ Hbuf, bf16* __restrict__ Abuf)
{
    const int d = (blockIdx.x << 8) + threadIdx.x;
    const int b = blockIdx.y;
    const int c = blockIdx.z;

    float A2[16];           // A[n] * log2(e)
#pragma unroll
    for (int n = 0; n < 16; ++n)
        A2[n] = -__expf(A_raw[n * 2048 + d]) * 1.44269504f;

    float h[16];
#pragma unroll
    for (int n = 0; n < 16; ++n) h[n] = 0.f;
    float sdt = 0.f;

    const size_t xbase = ((size_t)(b * 2048 + c * 128)) * 2048 + d;
    const bf16* xp = xc + xbase;
    const bf16* dp = delta + xbase;
    const bf16* bp = dbc + ((size_t)(b * 2048 + c * 128)) * 96 + 64;

    bf16 xa[4], da[4], xb[4], db[4], x2[4], d2[4], x3[4], d3[4];
    bf16x8 Ba[4][2], Bb[4][2];

#define LX1(X, D, g) do {                                           \
    _Pragma("unroll")                                               \
    for (int j = 0; j < 4; ++j) {                                   \
        const size_t tt = (size_t)((g) * 4 + j);                    \
        X[j] = xp[tt * 2048];                                       \
        D[j] = dp[tt * 2048];                                       \
    } } while (0)

#define LB1(Bv, g) do {                                             \
    _Pragma("unroll")                                               \
    for (int j = 0; j < 4; ++j) {                                   \
        const bf16* nb = bp + (size_t)((g) * 4 + j) * 96;           \
        Bv[j][0] = *(const bf16x8*)nb;                              \
        Bv[j][1] = *(const bf16x8*)(nb + 8);                        \
    } } while (0)

#define CG1(X, D, Bv) do {                                          \
    _Pragma("unroll")                                               \
    for (int j = 0; j < 4; ++j) {                                   \
        const float x  = (float)X[j];                               \
        const float dt = (float)D[j];                               \
        const float dx = dt * x;                                    \
        sdt += dt;                                                  \
        _Pragma("unroll")                                           \
        for (int k = 0; k < 8; ++k) {                               \
            float e = fast_exp2(dt * A2[k]);                        \
            h[k] = e * h[k] + (float)Bv[j][0][k] * dx;              \
        }                                                           \
        _Pragma("unroll")                                           \
        for (int k = 0; k < 8; ++k) {                               \
            float e = fast_exp2(dt * A2[k + 8]);                    \
            h[k + 8] = e * h[k + 8] + (float)Bv[j][1][k] * dx;      \
        }                                                           \
    } } while (0)

    LX1(xa, da, 0);
    LX1(xb, db, 1);
    LB1(Ba, 0);
    __builtin_amdgcn_sched_barrier(0);
#pragma unroll 1
    for (int g = 0; g < 32; g += 2) {
        LB1(Bb, g + 1);
        if (g + 2 < 32) LX1(x2, d2, g + 2);
        __builtin_amdgcn_sched_barrier(0);
        CG1(xa, da, Ba);
        if (g + 2 < 32) LB1(Ba, g + 2);
        if (g + 3 < 32) LX1(x3, d3, g + 3);
        __builtin_amdgcn_sched_barrier(0);
        CG1(xb, db, Bb);
#pragma unroll
        for (int j = 0; j < 4; ++j) {
            xa[j] = x2[j]; da[j] = d2[j];
            xb[j] = x3[j]; db[j] = d3[j];
        }
    }
#undef LX1
#undef LB1
#undef CG1

    const size_t hbase = (((size_t)b * 16 + c) * 2048 + d) * 16;
    f32x4* Hp = (f32x4*)(Hbuf + hbase);
#pragma unroll
    for (int r = 0; r < 4; ++r) {
        f32x4 v;
        v[0] = h[r * 4]; v[1] = h[r * 4 + 1];
        v[2] = h[r * 4 + 2]; v[3] = h[r * 4 + 3];
        Hp[r] = v;
    }
    bf16x8 a0, a1;
#pragma unroll
    for (int n = 0; n < 8; ++n) {
        a0[n] = (bf16)fast_exp2(A2[n] * sdt);
        a1[n] = (bf16)fast_exp2(A2[n + 8] * sdt);
    }
    *(bf16x8*)(Abuf + hbase) = a0;
    *(bf16x8*)(Abuf + hbase + 8) = a1;
}

__global__ __launch_bounds__(256) void scan_p2(
    float* __restrict__ Hbuf, const bf16* __restrict__ Abuf)
{
    const int id  = blockIdx.x * 256 + threadIdx.x;   // 131072 = b*32768+(d*16+n)
    const int b   = id >> 15;
    const int rem = id & 32767;
    const size_t base = (size_t)b * 16 * 32768 + rem;  // chunk stride 32768

    float Hv[16]; bf16 Av[16];
#pragma unroll
    for (int c = 0; c < 16; ++c) {
        Hv[c] = Hbuf[base + (size_t)c * 32768];
        Av[c] = Abuf[base + (size_t)c * 32768];
    }
    float ht = Hv[0];                      // H~_0 = H_0 (already stored)
#pragma unroll
    for (int c = 1; c < 16; ++c) {
        ht = Hv[c] + (float)Av[c] * ht;
        Hbuf[base + (size_t)c * 32768] = ht;
    }
}

__global__ __launch_bounds__(256, 2) void scan_p3(
    const bf16* __restrict__ delta, const bf16* __restrict__ dbc,
    const float* __restrict__ A_raw, const float* __restrict__ Dvec,
    const float* __restrict__ Hbuf, const bf16* xc, bf16* ry)
{
    const int d = (blockIdx.x << 8) + threadIdx.x;
    const int b = blockIdx.y;
    const int c = blockIdx.z;

    float A2[16];
#pragma unroll
    for (int n = 0; n < 16; ++n)
        A2[n] = -__expf(A_raw[n * 2048 + d]) * 1.44269504f;
    const float Dd = Dvec[d];

    float h[16];
    if (c > 0) {
        const f32x4* Hp = (const f32x4*)(
            Hbuf + (((size_t)b * 16 + (c - 1)) * 2048 + d) * 16);
#pragma unroll
        for (int r = 0; r < 4; ++r) {
            f32x4 v = Hp[r];
            h[r * 4] = v[0]; h[r * 4 + 1] = v[1];
            h[r * 4 + 2] = v[2]; h[r * 4 + 3] = v[3];
        }
    } else {
#pragma unroll
        for (int n = 0; n < 16; ++n) h[n] = 0.f;
    }

    const size_t xbase = ((size_t)(b * 2048 + c * 128)) * 2048 + d;
    const bf16* xp = xc + xbase;
    const bf16* dp = delta + xbase;
    const bf16* bp = dbc + ((size_t)(b * 2048 + c * 128)) * 96 + 64;
    bf16* yp = ry + xbase;

    bf16 xa[4], da[4], xb[4], db[4], x2[4], d2[4], x3[4], d3[4];
    bf16x8 Ba[4][2], Ca[4][2], Bb[4][2], Cb[4][2];

#define LX3(X, D, g) do {                                           \
    _Pragma("unroll")                                               \
    for (int j = 0; j < 4; ++j) {                                   \
        const size_t tt = (size_t)((g) * 4 + j);                    \
        X[j] = xp[tt * 2048];                                       \
        D[j] = dp[tt * 2048];                                       \
    } } while (0)

#define LB3(Bv, Cv, g) do {                                         \
    _Pragma("unroll")                                               \
    for (int j = 0; j < 4; ++j) {                                   \
        const bf16* nb = bp + (size_t)((g) * 4 + j) * 96;           \
        Bv[j][0] = *(const bf16x8*)nb;                              \
        Bv[j][1] = *(const bf16x8*)(nb + 8);                        \
        Cv[j][0] = *(const bf16x8*)(nb + 16);                       \
        Cv[j][1] = *(const bf16x8*)(nb + 24);                       \
    } } while (0)

#define CG3(X, D, Bv, Cv, g) do {                                   \
    _Pragma("unroll")                                               \
    for (int j = 0; j < 4; ++j) {                                   \
        const float x  = (float)X[j];                               \
        const float dt = (float)D[j];                               \
        const float dx = dt * x;                                    \
        float y = Dd * x;                                           \
        _Pragma("unroll")                                           \
        for (int k = 0; k < 8; ++k) {                               \
            float e = fast_exp2(dt * A2[k]);                        \
            h[k] = e * h[k] + (float)Bv[j][0][k] * dx;              \
            y += (float)Cv[j][0][k] * h[k];                         \
        }                                                           \
        _Pragma("unroll")                                           \
        for (int k = 0; k < 8; ++k) {                               \
            float e = fast_exp2(dt * A2[k + 8]);                    \
            h[k + 8] = e * h[k + 8] + (float)Bv[j][1][k] * dx;      \
            y += (float)Cv[j][1][k] * h[k + 8];                     \
        }                                                           \
        yp[(size_t)((g) * 4 + j) * 2048] = (bf16)y;                 \
    } } while (0)

    LX3(xa, da, 0);
    LX3(xb, db, 1);
    LB3(Ba, Ca, 0);
    __builtin_amdgcn_sched_barrier(0);
#pragma unroll 1
    for (int g = 0; g < 32; g += 2) {
        LB3(Bb, Cb, g + 1);
        if (g + 2 < 32) LX3(x2, d2, g + 2);
        __builtin_amdgcn_sched_barrier(0);
        CG3(xa, da, Ba, Ca, g);
        if (g + 2 < 32) LB3(Ba, Ca, g + 2);
        if (g + 3 < 32) LX3(x3, d3, g + 3);
        __builtin_amdgcn_sched_barrier(0);
        CG3(xb, db, Bb, Cb, g + 1);
#pragma unroll
        for (int j = 0; j < 4; ++j) {
            xa[j] = x2[j]; da[j] = d2[j];
            xb[j] = x3[j]; db[j] = d3[j];
        }
    }
#undef LX3
#undef LB3
#undef CG3
}

// ---------------------------------------------------------------------------
// launch.  Inputs: f32. Output: f32 (32 MiB).
// ws (>=64 MiB):
//   buf0 @0    (32Mi): xh -> delta -> y            (bf16)
//   buf1 @32Mi (32Mi): W_in_lo_b16 -> xc -> ry -> W_out_b16
// d_out (32 MiB, scratch until gemm7):
//   @0     dbc bf16 (1.5Mi)
//   @2Mi   gemm3 split-K partials f32 (12Mi)  ->  Hbuf f32 (8Mi, NC=16)
//          then after scan: W_in_hi_b16 (4Mi)
//   @10Mi  Abuf bf16 (4Mi)
//   @14Mi  W_x_b16 (384Ki) | @14.5Mi W_dt_b16 (256Ki)
//   @16Mi  x_b16 (16Mi, live until gemm6)
// ---------------------------------------------------------------------------
extern "C" void kernel_launch(void* const* d_in, const int* in_sizes, int n_in,
                              void* d_out, int out_size, void* d_ws, size_t ws_size,
                              hipStream_t stream)
{
    const float* x      = (const float*)d_in[0];
    const float* W_in   = (const float*)d_in[1];
    const float* conv_w = (const float*)d_in[2];
    const float* conv_b = (const float*)d_in[3];
    const float* W_x    = (const float*)d_in[4];
    const float* W_dt   = (const float*)d_in[5];
    const float* b_dt   = (const float*)d_in[6];
    const float* A_raw  = (const float*)d_in[7];
    const float* Dvec   = (const float*)d_in[8];
    const float* W_out  = (const float*)d_in[9];
    float* out = (float*)d_out;

    char* ws = (char*)d_ws;
    bf16*  buf0   = (bf16*)(ws + 0);           // xh -> delta -> y
    bf16*  buf1   = (bf16*)(ws + 33554432);    // W_in_lo -> xc -> ry -> W_out
    char*  dob    = (char*)d_out;
    bf16*  dbc    = (bf16*)dob;
    float* Pbuf   = (float*)(dob + 2097152);   // gemm3 partials (12Mi)
    float* Hbuf   = (float*)(dob + 2097152);   // scan H (8Mi), after reduce
    bf16*  Whi    = (bf16*)(dob + 2097152);    // W_in_hi (4Mi), after scan
    bf16*  Abuf   = (bf16*)(dob + 10485760);   // 4Mi
    bf16*  Wxb    = (bf16*)(dob + 14680064);   // 384Ki
    bf16*  Wdtb   = (bf16*)(dob + 15204352);   // 256Ki
    bf16*  xb     = (bf16*)(dob + 16777216);   // x bf16 (16Mi)
    bf16*  Wlo    = buf1;                       // W_in_lo (4Mi), pre-conv
    bf16*  Woutb  = buf1;                       // W_out (4Mi), post-gemm6

    // 0) one-time bf16 conversions
    cvt_bf16<<<dim3(4096), 256, 0, stream>>>(x, xb, 1048576);
    cvt_bf16<<<dim3(1024), 256, 0, stream>>>(W_in, Wlo, 262144);
    cvt_bf16<<<dim3(96),   256, 0, stream>>>(W_x, Wxb, 24576);
    cvt_bf16<<<dim3(64),   256, 0, stream>>>(W_dt, Wdtb, 16384);

    // 1) xh = x @ W_in[:2048]^T          M=8192 N=2048 K=1024
    gemm_bt<0, bf16><<<dim3(64, 16), 256, 0, stream>>>(
        xb, 1024, Wlo, 1024, buf0, 2048, 1024, 2048, nullptr, nullptr, 0);
    // 2) xc = silu(causal_conv(xh) + cb)
    conv_kernel<<<dim3(256, 4), 256, 0, stream>>>(buf0, conv_w, conv_b, buf1);
    // 3) dbc = xc @ W_x^T   M=8192 N=96 K=2048, split-K x4 -> f32 partials
    gemm_bt<0, float><<<dim3(64, 1, 4), 256, 0, stream>>>(
        buf1, 2048, Wxb, 2048, Pbuf, 96, 512, 96, nullptr, nullptr, 786432);
    reduce_dbc<<<dim3(768), 256, 0, stream>>>(Pbuf, dbc);
    // 4) delta = softplus(dt @ W_dt^T + b_dt)   (lda=96, K=64)
    gemm_bt<1, bf16><<<dim3(64, 16), 256, 0, stream>>>(
        dbc, 96, Wdtb, 64, buf0, 2048, 64, 2048, b_dt, nullptr, 0);
    // 5) chunk-parallel scan -> ry (ungated), in place over xc
    scan_p1<<<dim3(8, 4, 16), 256, 0, stream>>>(
        buf0, dbc, A_raw, buf1, Hbuf, Abuf);
    scan_p2<<<dim3(512), 256, 0, stream>>>(Hbuf, Abuf);
    scan_p3<<<dim3(8, 4, 16), 256, 0, stream>>>(
        buf0, dbc, A_raw, Dvec, Hbuf, buf1, buf1);
    // 6) y = ry * silu(x @ W_in[2048:]^T)   (fused z-GEMM + gate)
    cvt_bf16<<<dim3(1024), 256, 0, stream>>>(W_in + (size_t)2048 * 1024, Whi, 262144);
    gemm_bt<2, bf16><<<dim3(64, 16), 256, 0, stream>>>(
        xb, 1024, Whi, 1024, buf0, 2048, 1024, 2048, nullptr, buf1, 0);
    // 7) out = y @ W_out^T  (f32 store)  M=8192 N=1024 K=2048
    cvt_bf16<<<dim3(1024), 256, 0, stream>>>(W_out, Woutb, 262144);
    gemm_bt<0, float><<<dim3(64, 8), 256, 0, stream>>>(
        buf0, 2048, Woutb, 2048, out, 1024, 2048, 1024, nullptr, nullptr, 0);
}

// Round 6
// 468.853 us; speedup vs baseline: 1.0711x; 1.0711x over previous
//
#include <hip/hip_runtime.h>
#include <hip/hip_bf16.h>

typedef __bf16 bf16;
typedef __bf16 bf16x4 __attribute__((ext_vector_type(4)));
typedef __bf16 bf16x8 __attribute__((ext_vector_type(8)));
typedef float f32x4 __attribute__((ext_vector_type(4)));

__device__ __forceinline__ float fast_exp2(float x) {
#if __has_builtin(__builtin_amdgcn_exp2f)
    return __builtin_amdgcn_exp2f(x);
#else
    return exp2f(x);
#endif
}

// async global->LDS, 16B per lane. lds base must be wave-uniform; the HW
// writes lds + lane*16; the GLOBAL address is per-lane. (m97 pattern)
__device__ __forceinline__ void gload16(bf16* lds, const bf16* g) {
    __builtin_amdgcn_global_load_lds(
        (const __attribute__((address_space(1))) void*)g,
        (__attribute__((address_space(3))) void*)lds,
        16, 0, 0);
}

// ---------------------------------------------------------------------------
// f32 -> bf16 vectorized cast (8 elems / thread)
// ---------------------------------------------------------------------------
__device__ __forceinline__ bf16x8 cvt8(const float* p) {
    float4 a = *(const float4*)p;
    float4 b = *(const float4*)(p + 4);
    bf16x8 r;
    r[0] = (bf16)a.x; r[1] = (bf16)a.y; r[2] = (bf16)a.z; r[3] = (bf16)a.w;
    r[4] = (bf16)b.x; r[5] = (bf16)b.y; r[6] = (bf16)b.z; r[7] = (bf16)b.w;
    return r;
}

__global__ __launch_bounds__(256) void cvt_bf16(
    const float* __restrict__ in, bf16* __restrict__ out, int n8)
{
    int i = blockIdx.x * 256 + threadIdx.x;
    if (i < n8)
        *(bf16x8*)(out + (size_t)i * 8) = cvt8(in + (size_t)i * 8);
}

// ---------------------------------------------------------------------------
// C[M x N] = A[M x K] * B[N x K]^T   (A,B bf16; f32 accum; TC out)
// m97 structure: 128x128 tile, BK=32, linear LDS [128][32] (64B rows),
// global_load_lds dwordx4 staging (4 issues/thread/K-step), 2-barrier loop,
// 4 waves (2x2), each wave 4x4 of 16x16x32 MFMA.
// EPI==0: plain   EPI==1: softplus(acc + bias_f32[col])
// EPI==2: out = gmul_bf16[row,col] * silu(acc)
// grid.z splits K: block z computes K range [z*K, (z+1)*K), stores to
// C + z*zstride (f32 partials for split-K callers; zstride=0 otherwise).
// ---------------------------------------------------------------------------
template <int EPI, typename TC>
__global__ __launch_bounds__(256, 2) void gemm_bt(
    const bf16* __restrict__ A, int lda,
    const bf16* __restrict__ B, int ldb,
    TC* __restrict__ C, int ldc,
    int K, int Neff, const float* __restrict__ bias,
    const bf16* __restrict__ gmul, size_t zstride)
{
    __shared__ bf16 As[128 * 32];
    __shared__ bf16 Bs[128 * 32];

    const int tid  = threadIdx.x;
    const int lane = tid & 63;
    const int wave = tid >> 6;
    const int quad = lane >> 4;
    const int l16  = lane & 15;
    const int wm   = (wave >> 1) << 6;
    const int wn   = (wave & 1) << 6;
    const int bm   = blockIdx.x << 7;
    const int bn   = blockIdx.y << 7;
    const int kb   = blockIdx.z * K;

    // staging map: wave w covers LDS rows [w*16, +16)
    // lane l -> row +(l>>2), col (l&3)*8   (lds dest = uniform base + l*16B)
    const int srow = (wave << 4) + (lane >> 2);
    const int scol = (lane & 3) << 3;

    const bf16* Ag0 = A + (size_t)(bm + srow) * lda + kb + scol;
    const bf16* Ag1 = Ag0 + (size_t)lda * 64;
    int br0 = bn + srow;      br0 = br0 < Neff ? br0 : Neff - 1;
    int br1 = bn + srow + 64; br1 = br1 < Neff ? br1 : Neff - 1;
    const bf16* Bg0 = B + (size_t)br0 * ldb + kb + scol;
    const bf16* Bg1 = B + (size_t)br1 * ldb + kb + scol;

    bf16* Asd0 = As + wave * 512;           // wave-uniform LDS bases
    bf16* Asd1 = As + wave * 512 + 2048;
    bf16* Bsd0 = Bs + wave * 512;
    bf16* Bsd1 = Bs + wave * 512 + 2048;

    f32x4 acc[4][4] = {};

    for (int k0 = 0; k0 < K; k0 += 32) {
        if (k0) __syncthreads();            // protect LDS from overwrite
        gload16(Asd0, Ag0 + k0);
        gload16(Asd1, Ag1 + k0);
        gload16(Bsd0, Bg0 + k0);
        gload16(Bsd1, Bg1 + k0);
        __syncthreads();                    // drains vmcnt before barrier

        bf16x8 af[4], bfr[4];
#pragma unroll
        for (int i = 0; i < 4; ++i) {
            af[i]  = *(const bf16x8*)(As + (wm + i * 16 + l16) * 32 + quad * 8);
            bfr[i] = *(const bf16x8*)(Bs + (wn + i * 16 + l16) * 32 + quad * 8);
        }
#pragma unroll
        for (int mi = 0; mi < 4; ++mi)
#pragma unroll
            for (int ni = 0; ni < 4; ++ni)
                acc[mi][ni] = __builtin_amdgcn_mfma_f32_16x16x32_bf16(
                    af[mi], bfr[ni], acc[mi][ni], 0, 0, 0);
    }

    TC* Cz = C + (size_t)blockIdx.z * zstride;

    // C/D layout: row = quad*4 + r, col = l16  (m89-verified)
#pragma unroll
    for (int mi = 0; mi < 4; ++mi) {
        const int row = bm + wm + mi * 16 + quad * 4;
#pragma unroll
        for (int ni = 0; ni < 4; ++ni) {
            const int col = bn + wn + ni * 16 + l16;
            if (col < Neff) {
                float bc = (EPI == 1) ? bias[col] : 0.f;
#pragma unroll
                for (int r = 0; r < 4; ++r) {
                    float v = acc[mi][ni][r];
                    if (EPI == 1) {
                        v += bc;
                        v = (v > 15.f) ? v : log1pf(__expf(v));
                    } else if (EPI == 2) {
                        float g = v / (1.f + __expf(-v));   // silu(z)
                        v = (float)gmul[(size_t)(row + r) * ldc + col] * g;
                    }
                    Cz[(size_t)(row + r) * ldc + col] = (TC)v;
                }
            }
        }
    }
}

// ---------------------------------------------------------------------------
// split-K reduce: dbc[i] = bf16(sum_z P[z][i]),  n = 8192*96, 4 splits
// ---------------------------------------------------------------------------
__global__ __launch_bounds__(256) void reduce_dbc(
    const float* __restrict__ P, bf16* __restrict__ dbc)
{
    const size_t i = ((size_t)blockIdx.x * 256 + threadIdx.x) * 4;
    f32x4 s = *(const f32x4*)(P + i);
#pragma unroll
    for (int z = 1; z < 4; ++z) {
        f32x4 p = *(const f32x4*)(P + (size_t)z * 786432 + i);
        s[0] += p[0]; s[1] += p[1]; s[2] += p[2]; s[3] += p[3];
    }
    bf16x4 o;
    o[0] = (bf16)s[0]; o[1] = (bf16)s[1]; o[2] = (bf16)s[2]; o[3] = (bf16)s[3];
    *(bf16x4*)(dbc + i) = o;
}

// ---------------------------------------------------------------------------
// causal depthwise conv (k=4, left pad 3) + bias + SiLU: xh bf16 -> xc bf16
// t-tiled: each thread produces 8 consecutive t for 8 channels.
// ---------------------------------------------------------------------------
__global__ __launch_bounds__(256) void conv_kernel(
    const bf16* __restrict__ xh, const float* __restrict__ cw,
    const float* __restrict__ cb, bf16* __restrict__ xc)
{
    const int t0 = blockIdx.x << 3;          // 0..2040
    const int b  = blockIdx.y;
    const int d  = threadIdx.x * 8;

    float4 wv[8];           // wv[i] = taps 0..3 of channel d+i
#pragma unroll
    for (int i = 0; i < 8; ++i)
        wv[i] = *(const float4*)(cw + (d + i) * 4);

    float4 cb0 = *(const float4*)(cb + d);
    float4 cb1 = *(const float4*)(cb + d + 4);

    float acc[8][8];
#pragma unroll
    for (int k = 0; k < 8; ++k) {
        acc[k][0] = cb0.x; acc[k][1] = cb0.y; acc[k][2] = cb0.z; acc[k][3] = cb0.w;
        acc[k][4] = cb1.x; acc[k][5] = cb1.y; acc[k][6] = cb1.z; acc[k][7] = cb1.w;
    }

    const bf16* base = xh + ((size_t)b * 2048 + t0) * 2048 + d;

#pragma unroll
    for (int r = 0; r < 11; ++r) {
        const int t_in = t0 - 3 + r;
        if (t_in >= 0) {                     // uniform branch
            bf16x8 v = *(const bf16x8*)(base + (size_t)(r - 3) * 2048);
            float vf[8];
#pragma unroll
            for (int i = 0; i < 8; ++i) vf[i] = (float)v[i];
#pragma unroll
            for (int j = 0; j < 4; ++j) {    // tap j multiplies x[t-3+j]
                const int local = r - j;     // output index t0+local
                if (local >= 0 && local < 8) {
#pragma unroll
                    for (int i = 0; i < 8; ++i) {
                        float w = (j == 0) ? wv[i].x : (j == 1) ? wv[i].y
                                : (j == 2) ? wv[i].z : wv[i].w;
                        acc[local][i] += w * vf[i];
                    }
                }
            }
        }
    }

    bf16* ob = xc + ((size_t)b * 2048 + t0) * 2048 + d;
#pragma unroll
    for (int k = 0; k < 8; ++k) {
        bf16x8 o;
#pragma unroll
        for (int i = 0; i < 8; ++i) {
            float s = acc[k][i];
            o[i] = (bf16)(s / (1.f + __expf(-s)));
        }
        *(bf16x8*)(ob + (size_t)k * 2048) = o;
    }
}

// ---------------------------------------------------------------------------
// Chunk-parallel selective scan, NC=32 chunks x TC=64 t.
// thread = (b, c, d); all 16 states n in registers (r2 structure, the best
// measured).  NC=32 doubles wave count: 16 waves/CU cap (vs 8 at NC=16) --
// the scan is latency-bound and TLP is the one lever hipcc can't undo
// (r4/r5 post-mortem: source-level ILP pipelines get re-sunk by regalloc).
// Hbuf/Abuf layout: (b, c, d, n).
// ---------------------------------------------------------------------------
__global__ __launch_bounds__(256, 4) void scan_p1(
    const bf16* __restrict__ delta, const bf16* __restrict__ dbc,
    const float* __restrict__ A_raw, const bf16* __restrict__ xc,
    float* __restrict__ Hbuf, bf16* __restrict__ Abuf)
{
    const int d = (blockIdx.x << 8) + threadIdx.x;
    const int b = blockIdx.y;
    const int c = blockIdx.z;

    float A2[16];           // A[n] * log2(e)
#pragma unroll
    for (int n = 0; n < 16; ++n)
        A2[n] = -__expf(A_raw[n * 2048 + d]) * 1.44269504f;

    float h[16];
#pragma unroll
    for (int n = 0; n < 16; ++n) h[n] = 0.f;
    float sdt = 0.f;

    const size_t xbase = ((size_t)(b * 2048 + c * 64)) * 2048 + d;
    const bf16* xp = xc + xbase;
    const bf16* dp = delta + xbase;
    const bf16* bp = dbc + ((size_t)(b * 2048 + c * 64)) * 96 + 64;

    bf16 xr = xp[0], dr = dp[0];
    bf16x8 B0 = *(const bf16x8*)(bp);
    bf16x8 B1 = *(const bf16x8*)(bp + 8);

#pragma unroll 4
    for (int t = 0; t < 64; ++t) {
        const float x  = (float)xr;
        const float dt = (float)dr;
        const bf16x8 Bl = B0, Bh = B1;
        if (t < 63) {
            xr = xp[(size_t)(t + 1) * 2048];
            dr = dp[(size_t)(t + 1) * 2048];
            const bf16* nb = bp + (size_t)(t + 1) * 96;
            B0 = *(const bf16x8*)nb;
            B1 = *(const bf16x8*)(nb + 8);
        }
        const float dx = dt * x;
        sdt += dt;
#pragma unroll
        for (int n = 0; n < 8; ++n) {
            float e = fast_exp2(dt * A2[n]);
            h[n] = e * h[n] + (float)Bl[n] * dx;
        }
#pragma unroll
        for (int n = 0; n < 8; ++n) {
            float e = fast_exp2(dt * A2[n + 8]);
            h[n + 8] = e * h[n + 8] + (float)Bh[n] * dx;
        }
    }

    const size_t hbase = (((size_t)b * 32 + c) * 2048 + d) * 16;
    f32x4* Hp = (f32x4*)(Hbuf + hbase);
#pragma unroll
    for (int r = 0; r < 4; ++r) {
        f32x4 v;
        v[0] = h[r * 4]; v[1] = h[r * 4 + 1];
        v[2] = h[r * 4 + 2]; v[3] = h[r * 4 + 3];
        Hp[r] = v;
    }
    bf16x8 a0, a1;
#pragma unroll
    for (int n = 0; n < 8; ++n) {
        a0[n] = (bf16)fast_exp2(A2[n] * sdt);
        a1[n] = (bf16)fast_exp2(A2[n + 8] * sdt);
    }
    *(bf16x8*)(Abuf + hbase) = a0;
    *(bf16x8*)(Abuf + hbase + 8) = a1;
}

__global__ __launch_bounds__(256) void scan_p2(
    float* __restrict__ Hbuf, const bf16* __restrict__ Abuf)
{
    const int id  = blockIdx.x * 256 + threadIdx.x;   // 131072 = b*32768+(d*16+n)
    const int b   = id >> 15;
    const int rem = id & 32767;
    const size_t base = (size_t)b * 32 * 32768 + rem;  // chunk stride 32768

    float Hv[32]; bf16 Av[32];
#pragma unroll
    for (int c = 0; c < 32; ++c) {
        Hv[c] = Hbuf[base + (size_t)c * 32768];
        Av[c] = Abuf[base + (size_t)c * 32768];
    }
    float ht = Hv[0];                      // H~_0 = H_0 (already stored)
#pragma unroll
    for (int c = 1; c < 32; ++c) {
        ht = Hv[c] + (float)Av[c] * ht;
        Hbuf[base + (size_t)c * 32768] = ht;
    }
}

__global__ __launch_bounds__(256, 4) void scan_p3(
    const bf16* __restrict__ delta, const bf16* __restrict__ dbc,
    const float* __restrict__ A_raw, const float* __restrict__ Dvec,
    const float* __restrict__ Hbuf, const bf16* xc, bf16* ry)
{
    const int d = (blockIdx.x << 8) + threadIdx.x;
    const int b = blockIdx.y;
    const int c = blockIdx.z;

    float A2[16];
#pragma unroll
    for (int n = 0; n < 16; ++n)
        A2[n] = -__expf(A_raw[n * 2048 + d]) * 1.44269504f;
    const float Dd = Dvec[d];

    float h[16];
    if (c > 0) {
        const f32x4* Hp = (const f32x4*)(
            Hbuf + (((size_t)b * 32 + (c - 1)) * 2048 + d) * 16);
#pragma unroll
        for (int r = 0; r < 4; ++r) {
            f32x4 v = Hp[r];
            h[r * 4] = v[0]; h[r * 4 + 1] = v[1];
            h[r * 4 + 2] = v[2]; h[r * 4 + 3] = v[3];
        }
    } else {
#pragma unroll
        for (int n = 0; n < 16; ++n) h[n] = 0.f;
    }

    const size_t xbase = ((size_t)(b * 2048 + c * 64)) * 2048 + d;
    const bf16* xp = xc + xbase;
    const bf16* dp = delta + xbase;
    const bf16* bp = dbc + ((size_t)(b * 2048 + c * 64)) * 96 + 64;
    bf16* yp = ry + xbase;

    bf16 xr = xp[0], dr = dp[0];
    bf16x8 B0 = *(const bf16x8*)(bp);
    bf16x8 B1 = *(const bf16x8*)(bp + 8);
    bf16x8 C0 = *(const bf16x8*)(bp + 16);
    bf16x8 C1 = *(const bf16x8*)(bp + 24);

#pragma unroll 4
    for (int t = 0; t < 64; ++t) {
        const float x  = (float)xr;
        const float dt = (float)dr;
        const bf16x8 Bl = B0, Bh = B1, Cl = C0, Ch = C1;
        if (t < 63) {
            xr = xp[(size_t)(t + 1) * 2048];
            dr = dp[(size_t)(t + 1) * 2048];
            const bf16* nb = bp + (size_t)(t + 1) * 96;
            B0 = *(const bf16x8*)nb;
            B1 = *(const bf16x8*)(nb + 8);
            C0 = *(const bf16x8*)(nb + 16);
            C1 = *(const bf16x8*)(nb + 24);
        }
        const float dx = dt * x;
        float y = Dd * x;
#pragma unroll
        for (int n = 0; n < 8; ++n) {
            float e = fast_exp2(dt * A2[n]);
            h[n] = e * h[n] + (float)Bl[n] * dx;
            y += (float)Cl[n] * h[n];
        }
#pragma unroll
        for (int n = 0; n < 8; ++n) {
            float e = fast_exp2(dt * A2[n + 8]);
            h[n + 8] = e * h[n + 8] + (float)Bh[n] * dx;
            y += (float)Ch[n] * h[n + 8];
        }
        yp[(size_t)t * 2048] = (bf16)y;
    }
}

// ---------------------------------------------------------------------------
// launch.  Inputs: f32. Output: f32 (32 MiB).
// ws (>=64 MiB):
//   buf0 @0    (32Mi): xh -> delta -> y            (bf16)
//   buf1 @32Mi (32Mi): W_in_lo_b16 -> xc -> ry -> W_out_b16
// d_out (32 MiB) timeline (xb is re-created for gemm6; NC=32 H/A need 24Mi):
//   @0     dbc bf16 (1.5Mi)                        [gemm3..scan_p3]
//   @2Mi   xb_1 (16Mi)        [cvt..gemm1]
//       -> Pbuf f32 (12Mi)    [gemm3..reduce]
//       -> Hbuf f32 (16Mi)    [scan_p1..scan_p3]
//       -> xb_2 (16Mi)        [cvt..gemm6]
//   @18Mi  Abuf bf16 (8Mi)    [scan_p1..scan_p2]
//       -> Whi (4Mi)          [cvt..gemm6]
//   @26Mi  Wxb (384Ki) [..gemm3] | @26.5Mi Wdtb (256Ki) [..gemm4]
// gemm7 writes out over all of d_out (reads only ws).
// ---------------------------------------------------------------------------
extern "C" void kernel_launch(void* const* d_in, const int* in_sizes, int n_in,
                              void* d_out, int out_size, void* d_ws, size_t ws_size,
                              hipStream_t stream)
{
    const float* x      = (const float*)d_in[0];
    const float* W_in   = (const float*)d_in[1];
    const float* conv_w = (const float*)d_in[2];
    const float* conv_b = (const float*)d_in[3];
    const float* W_x    = (const float*)d_in[4];
    const float* W_dt   = (const float*)d_in[5];
    const float* b_dt   = (const float*)d_in[6];
    const float* A_raw  = (const float*)d_in[7];
    const float* Dvec   = (const float*)d_in[8];
    const float* W_out  = (const float*)d_in[9];
    float* out = (float*)d_out;

    char* ws = (char*)d_ws;
    bf16*  buf0   = (bf16*)(ws + 0);           // xh -> delta -> y
    bf16*  buf1   = (bf16*)(ws + 33554432);    // W_in_lo -> xc -> ry -> W_out
    char*  dob    = (char*)d_out;
    bf16*  dbc    = (bf16*)dob;
    bf16*  xb1    = (bf16*)(dob + 2097152);    // x bf16 (16Mi), until gemm1
    float* Pbuf   = (float*)(dob + 2097152);   // gemm3 partials (12Mi)
    float* Hbuf   = (float*)(dob + 2097152);   // scan H f32 (16Mi, NC=32)
    bf16*  xb2    = (bf16*)(dob + 2097152);    // x bf16 again, for gemm6
    bf16*  Abuf   = (bf16*)(dob + 18874368);   // 8Mi
    bf16*  Whi    = (bf16*)(dob + 18874368);   // W_in_hi (4Mi), after scan
    bf16*  Wxb    = (bf16*)(dob + 27262976);   // 384Ki
    bf16*  Wdtb   = (bf16*)(dob + 27787264);   // 256Ki
    bf16*  Wlo    = buf1;                       // W_in_lo (4Mi), pre-conv
    bf16*  Woutb  = buf1;                       // W_out (4Mi), post-gemm6

    // 0) one-time bf16 conversions
    cvt_bf16<<<dim3(4096), 256, 0, stream>>>(x, xb1, 1048576);
    cvt_bf16<<<dim3(1024), 256, 0, stream>>>(W_in, Wlo, 262144);
    cvt_bf16<<<dim3(96),   256, 0, stream>>>(W_x, Wxb, 24576);
    cvt_bf16<<<dim3(64),   256, 0, stream>>>(W_dt, Wdtb, 16384);

    // 1) xh = x @ W_in[:2048]^T          M=8192 N=2048 K=1024
    gemm_bt<0, bf16><<<dim3(64, 16), 256, 0, stream>>>(
        xb1, 1024, Wlo, 1024, buf0, 2048, 1024, 2048, nullptr, nullptr, 0);
    // 2) xc = silu(causal_conv(xh) + cb)
    conv_kernel<<<dim3(256, 4), 256, 0, stream>>>(buf0, conv_w, conv_b, buf1);
    // 3) dbc = xc @ W_x^T   M=8192 N=96 K=2048, split-K x4 -> f32 partials
    gemm_bt<0, float><<<dim3(64, 1, 4), 256, 0, stream>>>(
        buf1, 2048, Wxb, 2048, Pbuf, 96, 512, 96, nullptr, nullptr, 786432);
    reduce_dbc<<<dim3(768), 256, 0, stream>>>(Pbuf, dbc);
    // 4) delta = softplus(dt @ W_dt^T + b_dt)   (lda=96, K=64)
    gemm_bt<1, bf16><<<dim3(64, 16), 256, 0, stream>>>(
        dbc, 96, Wdtb, 64, buf0, 2048, 64, 2048, b_dt, nullptr, 0);
    // 5) chunk-parallel scan (NC=32) -> ry (ungated), in place over xc
    scan_p1<<<dim3(8, 4, 32), 256, 0, stream>>>(
        buf0, dbc, A_raw, buf1, Hbuf, Abuf);
    scan_p2<<<dim3(512), 256, 0, stream>>>(Hbuf, Abuf);
    scan_p3<<<dim3(8, 4, 32), 256, 0, stream>>>(
        buf0, dbc, A_raw, Dvec, Hbuf, buf1, buf1);
    // 6) y = ry * silu(x @ W_in[2048:]^T)   (fused z-GEMM + gate)
    cvt_bf16<<<dim3(4096), 256, 0, stream>>>(x, xb2, 1048576);
    cvt_bf16<<<dim3(1024), 256, 0, stream>>>(W_in + (size_t)2048 * 1024, Whi, 262144);
    gemm_bt<2, bf16><<<dim3(64, 16), 256, 0, stream>>>(
        xb2, 1024, Whi, 1024, buf0, 2048, 1024, 2048, nullptr, buf1, 0);
    // 7) out = y @ W_out^T  (f32 store)  M=8192 N=1024 K=2048
    cvt_bf16<<<dim3(1024), 256, 0, stream>>>(W_out, Woutb, 262144);
    gemm_bt<0, float><<<dim3(64, 8), 256, 0, stream>>>(
        buf0, 2048, Woutb, 2048, out, 1024, 2048, 1024, nullptr, nullptr, 0);
}

// Round 7
// 426.994 us; speedup vs baseline: 1.1761x; 1.0980x over previous
//
#include <hip/hip_runtime.h>
#include <hip/hip_bf16.h>

typedef __bf16 bf16;
typedef __bf16 bf16x4 __attribute__((ext_vector_type(4)));
typedef __bf16 bf16x8 __attribute__((ext_vector_type(8)));
typedef float f32x4 __attribute__((ext_vector_type(4)));

__device__ __forceinline__ float fast_exp2(float x) {
#if __has_builtin(__builtin_amdgcn_exp2f)
    return __builtin_amdgcn_exp2f(x);
#else
    return exp2f(x);
#endif
}

// fast natural log via v_log_f32 (log2) -- log1pf() lowers to the slow
// precise OCML path (~260 VALU inst/elem measured in r6's delta-GEMM).
__device__ __forceinline__ float fast_log(float x) {
#if __has_builtin(__builtin_amdgcn_logf)
    return __builtin_amdgcn_logf(x) * 0.6931471805599453f;
#else
    return __logf(x);
#endif
}

// async global->LDS, 16B per lane. lds base must be wave-uniform; the HW
// writes lds + lane*16; the GLOBAL address is per-lane. (m97 pattern)
__device__ __forceinline__ void gload16(bf16* lds, const bf16* g) {
    __builtin_amdgcn_global_load_lds(
        (const __attribute__((address_space(1))) void*)g,
        (__attribute__((address_space(3))) void*)lds,
        16, 0, 0);
}

// ---------------------------------------------------------------------------
// f32 -> bf16 vectorized cast (8 elems / thread)
// ---------------------------------------------------------------------------
__device__ __forceinline__ bf16x8 cvt8(const float* p) {
    float4 a = *(const float4*)p;
    float4 b = *(const float4*)(p + 4);
    bf16x8 r;
    r[0] = (bf16)a.x; r[1] = (bf16)a.y; r[2] = (bf16)a.z; r[3] = (bf16)a.w;
    r[4] = (bf16)b.x; r[5] = (bf16)b.y; r[6] = (bf16)b.z; r[7] = (bf16)b.w;
    return r;
}

__global__ __launch_bounds__(256) void cvt_bf16(
    const float* __restrict__ in, bf16* __restrict__ out, int n8)
{
    int i = blockIdx.x * 256 + threadIdx.x;
    if (i < n8)
        *(bf16x8*)(out + (size_t)i * 8) = cvt8(in + (size_t)i * 8);
}

// ---------------------------------------------------------------------------
// C[M x N] = A[M x K] * B[N x K]^T   (A,B bf16; f32 accum; TC out)
// m97 structure: 128x128 tile, BK=32, linear LDS [128][32] (64B rows),
// global_load_lds dwordx4 staging (4 issues/thread/K-step), 2-barrier loop,
// 4 waves (2x2), each wave 4x4 of 16x16x32 MFMA.
// EPI==0: plain   EPI==1: softplus(acc + bias_f32[col])
// EPI==2: out = gmul_bf16[row,col] * silu(acc)
// grid.z splits K: block z computes K range [z*K, (z+1)*K), stores to
// C + z*zstride (f32 partials for split-K callers; zstride=0 otherwise).
// ---------------------------------------------------------------------------
template <int EPI, typename TC>
__global__ __launch_bounds__(256, 2) void gemm_bt(
    const bf16* __restrict__ A, int lda,
    const bf16* __restrict__ B, int ldb,
    TC* __restrict__ C, int ldc,
    int K, int Neff, const float* __restrict__ bias,
    const bf16* __restrict__ gmul, size_t zstride)
{
    __shared__ bf16 As[128 * 32];
    __shared__ bf16 Bs[128 * 32];

    const int tid  = threadIdx.x;
    const int lane = tid & 63;
    const int wave = tid >> 6;
    const int quad = lane >> 4;
    const int l16  = lane & 15;
    const int wm   = (wave >> 1) << 6;
    const int wn   = (wave & 1) << 6;
    const int bm   = blockIdx.x << 7;
    const int bn   = blockIdx.y << 7;
    const int kb   = blockIdx.z * K;

    // staging map: wave w covers LDS rows [w*16, +16)
    // lane l -> row +(l>>2), col (l&3)*8   (lds dest = uniform base + l*16B)
    const int srow = (wave << 4) + (lane >> 2);
    const int scol = (lane & 3) << 3;

    const bf16* Ag0 = A + (size_t)(bm + srow) * lda + kb + scol;
    const bf16* Ag1 = Ag0 + (size_t)lda * 64;
    int br0 = bn + srow;      br0 = br0 < Neff ? br0 : Neff - 1;
    int br1 = bn + srow + 64; br1 = br1 < Neff ? br1 : Neff - 1;
    const bf16* Bg0 = B + (size_t)br0 * ldb + kb + scol;
    const bf16* Bg1 = B + (size_t)br1 * ldb + kb + scol;

    bf16* Asd0 = As + wave * 512;           // wave-uniform LDS bases
    bf16* Asd1 = As + wave * 512 + 2048;
    bf16* Bsd0 = Bs + wave * 512;
    bf16* Bsd1 = Bs + wave * 512 + 2048;

    f32x4 acc[4][4] = {};

    for (int k0 = 0; k0 < K; k0 += 32) {
        if (k0) __syncthreads();            // protect LDS from overwrite
        gload16(Asd0, Ag0 + k0);
        gload16(Asd1, Ag1 + k0);
        gload16(Bsd0, Bg0 + k0);
        gload16(Bsd1, Bg1 + k0);
        __syncthreads();                    // drains vmcnt before barrier

        bf16x8 af[4], bfr[4];
#pragma unroll
        for (int i = 0; i < 4; ++i) {
            af[i]  = *(const bf16x8*)(As + (wm + i * 16 + l16) * 32 + quad * 8);
            bfr[i] = *(const bf16x8*)(Bs + (wn + i * 16 + l16) * 32 + quad * 8);
        }
#pragma unroll
        for (int mi = 0; mi < 4; ++mi)
#pragma unroll
            for (int ni = 0; ni < 4; ++ni)
                acc[mi][ni] = __builtin_amdgcn_mfma_f32_16x16x32_bf16(
                    af[mi], bfr[ni], acc[mi][ni], 0, 0, 0);
    }

    TC* Cz = C + (size_t)blockIdx.z * zstride;

    // C/D layout: row = quad*4 + r, col = l16  (m89-verified)
#pragma unroll
    for (int mi = 0; mi < 4; ++mi) {
        const int row = bm + wm + mi * 16 + quad * 4;
#pragma unroll
        for (int ni = 0; ni < 4; ++ni) {
            const int col = bn + wn + ni * 16 + l16;
            if (col < Neff) {
                float bc = (EPI == 1) ? bias[col] : 0.f;
#pragma unroll
                for (int r = 0; r < 4; ++r) {
                    float v = acc[mi][ni][r];
                    if (EPI == 1) {
                        v += bc;
                        // softplus via hw exp/log (fast_log): ~8 VALU/elem
                        float sp = fast_log(1.f + __expf(v));
                        v = (v > 15.f) ? v : sp;
                    } else if (EPI == 2) {
                        float g = v / (1.f + __expf(-v));   // silu(z)
                        v = (float)gmul[(size_t)(row + r) * ldc + col] * g;
                    }
                    Cz[(size_t)(row + r) * ldc + col] = (TC)v;
                }
            }
        }
    }
}

// ---------------------------------------------------------------------------
// split-K reduce: dbc[i] = bf16(sum_z P[z][i]),  n = 8192*96, 4 splits
// ---------------------------------------------------------------------------
__global__ __launch_bounds__(256) void reduce_dbc(
    const float* __restrict__ P, bf16* __restrict__ dbc)
{
    const size_t i = ((size_t)blockIdx.x * 256 + threadIdx.x) * 4;
    f32x4 s = *(const f32x4*)(P + i);
#pragma unroll
    for (int z = 1; z < 4; ++z) {
        f32x4 p = *(const f32x4*)(P + (size_t)z * 786432 + i);
        s[0] += p[0]; s[1] += p[1]; s[2] += p[2]; s[3] += p[3];
    }
    bf16x4 o;
    o[0] = (bf16)s[0]; o[1] = (bf16)s[1]; o[2] = (bf16)s[2]; o[3] = (bf16)s[3];
    *(bf16x4*)(dbc + i) = o;
}

// ---------------------------------------------------------------------------
// causal depthwise conv (k=4, left pad 3) + bias + SiLU: xh bf16 -> xc bf16
// t-tiled: each thread produces 8 consecutive t for 8 channels.
// ---------------------------------------------------------------------------
__global__ __launch_bounds__(256) void conv_kernel(
    const bf16* __restrict__ xh, const float* __restrict__ cw,
    const float* __restrict__ cb, bf16* __restrict__ xc)
{
    const int t0 = blockIdx.x << 3;          // 0..2040
    const int b  = blockIdx.y;
    const int d  = threadIdx.x * 8;

    float4 wv[8];           // wv[i] = taps 0..3 of channel d+i
#pragma unroll
    for (int i = 0; i < 8; ++i)
        wv[i] = *(const float4*)(cw + (d + i) * 4);

    float4 cb0 = *(const float4*)(cb + d);
    float4 cb1 = *(const float4*)(cb + d + 4);

    float acc[8][8];
#pragma unroll
    for (int k = 0; k < 8; ++k) {
        acc[k][0] = cb0.x; acc[k][1] = cb0.y; acc[k][2] = cb0.z; acc[k][3] = cb0.w;
        acc[k][4] = cb1.x; acc[k][5] = cb1.y; acc[k][6] = cb1.z; acc[k][7] = cb1.w;
    }

    const bf16* base = xh + ((size_t)b * 2048 + t0) * 2048 + d;

#pragma unroll
    for (int r = 0; r < 11; ++r) {
        const int t_in = t0 - 3 + r;
        if (t_in >= 0) {                     // uniform branch
            bf16x8 v = *(const bf16x8*)(base + (size_t)(r - 3) * 2048);
            float vf[8];
#pragma unroll
            for (int i = 0; i < 8; ++i) vf[i] = (float)v[i];
#pragma unroll
            for (int j = 0; j < 4; ++j) {    // tap j multiplies x[t-3+j]
                const int local = r - j;     // output index t0+local
                if (local >= 0 && local < 8) {
#pragma unroll
                    for (int i = 0; i < 8; ++i) {
                        float w = (j == 0) ? wv[i].x : (j == 1) ? wv[i].y
                                : (j == 2) ? wv[i].z : wv[i].w;
                        acc[local][i] += w * vf[i];
                    }
                }
            }
        }
    }

    bf16* ob = xc + ((size_t)b * 2048 + t0) * 2048 + d;
#pragma unroll
    for (int k = 0; k < 8; ++k) {
        bf16x8 o;
#pragma unroll
        for (int i = 0; i < 8; ++i) {
            float s = acc[k][i];
            o[i] = (bf16)(s / (1.f + __expf(-s)));
        }
        *(bf16x8*)(ob + (size_t)k * 2048) = o;
    }
}

// ---------------------------------------------------------------------------
// Chunk-parallel selective scan, NC=32 chunks x TC=64 t.
// thread = (b, c, d); all 16 states n in registers (r2 structure, the best
// measured).  NC=32 doubles wave count: 16 waves/CU cap (vs 8 at NC=16) --
// the scan is latency-bound and TLP is the one lever hipcc can't undo
// (r4/r5 post-mortem: source-level ILP pipelines get re-sunk by regalloc).
// Hbuf/Abuf layout: (b, c, d, n).
// ---------------------------------------------------------------------------
__global__ __launch_bounds__(256, 4) void scan_p1(
    const bf16* __restrict__ delta, const bf16* __restrict__ dbc,
    const float* __restrict__ A_raw, const bf16* __restrict__ xc,
    float* __restrict__ Hbuf, bf16* __restrict__ Abuf)
{
    const int d = (blockIdx.x << 8) + threadIdx.x;
    const int b = blockIdx.y;
    const int c = blockIdx.z;

    float A2[16];           // A[n] * log2(e)
#pragma unroll
    for (int n = 0; n < 16; ++n)
        A2[n] = -__expf(A_raw[n * 2048 + d]) * 1.44269504f;

    float h[16];
#pragma unroll
    for (int n = 0; n < 16; ++n) h[n] = 0.f;
    float sdt = 0.f;

    const size_t xbase = ((size_t)(b * 2048 + c * 64)) * 2048 + d;
    const bf16* xp = xc + xbase;
    const bf16* dp = delta + xbase;
    const bf16* bp = dbc + ((size_t)(b * 2048 + c * 64)) * 96 + 64;

    bf16 xr = xp[0], dr = dp[0];
    bf16x8 B0 = *(const bf16x8*)(bp);
    bf16x8 B1 = *(const bf16x8*)(bp + 8);

#pragma unroll 4
    for (int t = 0; t < 64; ++t) {
        const float x  = (float)xr;
        const float dt = (float)dr;
        const bf16x8 Bl = B0, Bh = B1;
        if (t < 63) {
            xr = xp[(size_t)(t + 1) * 2048];
            dr = dp[(size_t)(t + 1) * 2048];
            const bf16* nb = bp + (size_t)(t + 1) * 96;
            B0 = *(const bf16x8*)nb;
            B1 = *(const bf16x8*)(nb + 8);
        }
        const float dx = dt * x;
        sdt += dt;
#pragma unroll
        for (int n = 0; n < 8; ++n) {
            float e = fast_exp2(dt * A2[n]);
            h[n] = e * h[n] + (float)Bl[n] * dx;
        }
#pragma unroll
        for (int n = 0; n < 8; ++n) {
            float e = fast_exp2(dt * A2[n + 8]);
            h[n + 8] = e * h[n + 8] + (float)Bh[n] * dx;
        }
    }

    const size_t hbase = (((size_t)b * 32 + c) * 2048 + d) * 16;
    f32x4* Hp = (f32x4*)(Hbuf + hbase);
#pragma unroll
    for (int r = 0; r < 4; ++r) {
        f32x4 v;
        v[0] = h[r * 4]; v[1] = h[r * 4 + 1];
        v[2] = h[r * 4 + 2]; v[3] = h[r * 4 + 3];
        Hp[r] = v;
    }
    bf16x8 a0, a1;
#pragma unroll
    for (int n = 0; n < 8; ++n) {
        a0[n] = (bf16)fast_exp2(A2[n] * sdt);
        a1[n] = (bf16)fast_exp2(A2[n + 8] * sdt);
    }
    *(bf16x8*)(Abuf + hbase) = a0;
    *(bf16x8*)(Abuf + hbase + 8) = a1;
}

__global__ __launch_bounds__(256) void scan_p2(
    float* __restrict__ Hbuf, const bf16* __restrict__ Abuf)
{
    const int id  = blockIdx.x * 256 + threadIdx.x;   // 131072 = b*32768+(d*16+n)
    const int b   = id >> 15;
    const int rem = id & 32767;
    const size_t base = (size_t)b * 32 * 32768 + rem;  // chunk stride 32768

    float Hv[32]; bf16 Av[32];
#pragma unroll
    for (int c = 0; c < 32; ++c) {
        Hv[c] = Hbuf[base + (size_t)c * 32768];
        Av[c] = Abuf[base + (size_t)c * 32768];
    }
    float ht = Hv[0];                      // H~_0 = H_0 (already stored)
#pragma unroll
    for (int c = 1; c < 32; ++c) {
        ht = Hv[c] + (float)Av[c] * ht;
        Hbuf[base + (size_t)c * 32768] = ht;
    }
}

__global__ __launch_bounds__(256, 4) void scan_p3(
    const bf16* __restrict__ delta, const bf16* __restrict__ dbc,
    const float* __restrict__ A_raw, const float* __restrict__ Dvec,
    const float* __restrict__ Hbuf, const bf16* xc, bf16* ry)
{
    const int d = (blockIdx.x << 8) + threadIdx.x;
    const int b = blockIdx.y;
    const int c = blockIdx.z;

    float A2[16];
#pragma unroll
    for (int n = 0; n < 16; ++n)
        A2[n] = -__expf(A_raw[n * 2048 + d]) * 1.44269504f;
    const float Dd = Dvec[d];

    float h[16];
    if (c > 0) {
        const f32x4* Hp = (const f32x4*)(
            Hbuf + (((size_t)b * 32 + (c - 1)) * 2048 + d) * 16);
#pragma unroll
        for (int r = 0; r < 4; ++r) {
            f32x4 v = Hp[r];
            h[r * 4] = v[0]; h[r * 4 + 1] = v[1];
            h[r * 4 + 2] = v[2]; h[r * 4 + 3] = v[3];
        }
    } else {
#pragma unroll
        for (int n = 0; n < 16; ++n) h[n] = 0.f;
    }

    const size_t xbase = ((size_t)(b * 2048 + c * 64)) * 2048 + d;
    const bf16* xp = xc + xbase;
    const bf16* dp = delta + xbase;
    const bf16* bp = dbc + ((size_t)(b * 2048 + c * 64)) * 96 + 64;
    bf16* yp = ry + xbase;

    bf16 xr = xp[0], dr = dp[0];
    bf16x8 B0 = *(const bf16x8*)(bp);
    bf16x8 B1 = *(const bf16x8*)(bp + 8);
    bf16x8 C0 = *(const bf16x8*)(bp + 16);
    bf16x8 C1 = *(const bf16x8*)(bp + 24);

#pragma unroll 4
    for (int t = 0; t < 64; ++t) {
        const float x  = (float)xr;
        const float dt = (float)dr;
        const bf16x8 Bl = B0, Bh = B1, Cl = C0, Ch = C1;
        if (t < 63) {
            xr = xp[(size_t)(t + 1) * 2048];
            dr = dp[(size_t)(t + 1) * 2048];
            const bf16* nb = bp + (size_t)(t + 1) * 96;
            B0 = *(const bf16x8*)nb;
            B1 = *(const bf16x8*)(nb + 8);
            C0 = *(const bf16x8*)(nb + 16);
            C1 = *(const bf16x8*)(nb + 24);
        }
        const float dx = dt * x;
        float y = Dd * x;
#pragma unroll
        for (int n = 0; n < 8; ++n) {
            float e = fast_exp2(dt * A2[n]);
            h[n] = e * h[n] + (float)Bl[n] * dx;
            y += (float)Cl[n] * h[n];
        }
#pragma unroll
        for (int n = 0; n < 8; ++n) {
            float e = fast_exp2(dt * A2[n + 8]);
            h[n + 8] = e * h[n + 8] + (float)Bh[n] * dx;
            y += (float)Ch[n] * h[n + 8];
        }
        yp[(size_t)t * 2048] = (bf16)y;
    }
}

// ---------------------------------------------------------------------------
// launch.  Inputs: f32. Output: f32 (32 MiB).
// ws (>=64 MiB):
//   buf0 @0    (32Mi): xh -> delta -> y            (bf16)
//   buf1 @32Mi (32Mi): W_in_lo_b16 -> xc -> ry -> W_out_b16
// d_out (32 MiB) timeline (xb is re-created for gemm6; NC=32 H/A need 24Mi):
//   @0     dbc bf16 (1.5Mi)                        [gemm3..scan_p3]
//   @2Mi   xb_1 (16Mi)        [cvt..gemm1]
//       -> Pbuf f32 (12Mi)    [gemm3..reduce]
//       -> Hbuf f32 (16Mi)    [scan_p1..scan_p3]
//       -> xb_2 (16Mi)        [cvt..gemm6]
//   @18Mi  Abuf bf16 (8Mi)    [scan_p1..scan_p2]
//       -> Whi (4Mi)          [cvt..gemm6]
//   @26Mi  Wxb (384Ki) [..gemm3] | @26.5Mi Wdtb (256Ki) [..gemm4]
// gemm7 writes out over all of d_out (reads only ws).
// ---------------------------------------------------------------------------
extern "C" void kernel_launch(void* const* d_in, const int* in_sizes, int n_in,
                              void* d_out, int out_size, void* d_ws, size_t ws_size,
                              hipStream_t stream)
{
    const float* x      = (const float*)d_in[0];
    const float* W_in   = (const float*)d_in[1];
    const float* conv_w = (const float*)d_in[2];
    const float* conv_b = (const float*)d_in[3];
    const float* W_x    = (const float*)d_in[4];
    const float* W_dt   = (const float*)d_in[5];
    const float* b_dt   = (const float*)d_in[6];
    const float* A_raw  = (const float*)d_in[7];
    const float* Dvec   = (const float*)d_in[8];
    const float* W_out  = (const float*)d_in[9];
    float* out = (float*)d_out;

    char* ws = (char*)d_ws;
    bf16*  buf0   = (bf16*)(ws + 0);           // xh -> delta -> y
    bf16*  buf1   = (bf16*)(ws + 33554432);    // W_in_lo -> xc -> ry -> W_out
    char*  dob    = (char*)d_out;
    bf16*  dbc    = (bf16*)dob;
    bf16*  xb1    = (bf16*)(dob + 2097152);    // x bf16 (16Mi), until gemm1
    float* Pbuf   = (float*)(dob + 2097152);   // gemm3 partials (12Mi)
    float* Hbuf   = (float*)(dob + 2097152);   // scan H f32 (16Mi, NC=32)
    bf16*  xb2    = (bf16*)(dob + 2097152);    // x bf16 again, for gemm6
    bf16*  Abuf   = (bf16*)(dob + 18874368);   // 8Mi
    bf16*  Whi    = (bf16*)(dob + 18874368);   // W_in_hi (4Mi), after scan
    bf16*  Wxb    = (bf16*)(dob + 27262976);   // 384Ki
    bf16*  Wdtb   = (bf16*)(dob + 27787264);   // 256Ki
    bf16*  Wlo    = buf1;                       // W_in_lo (4Mi), pre-conv
    bf16*  Woutb  = buf1;                       // W_out (4Mi), post-gemm6

    // 0) one-time bf16 conversions
    cvt_bf16<<<dim3(4096), 256, 0, stream>>>(x, xb1, 1048576);
    cvt_bf16<<<dim3(1024), 256, 0, stream>>>(W_in, Wlo, 262144);
    cvt_bf16<<<dim3(96),   256, 0, stream>>>(W_x, Wxb, 24576);
    cvt_bf16<<<dim3(64),   256, 0, stream>>>(W_dt, Wdtb, 16384);

    // 1) xh = x @ W_in[:2048]^T          M=8192 N=2048 K=1024
    gemm_bt<0, bf16><<<dim3(64, 16), 256, 0, stream>>>(
        xb1, 1024, Wlo, 1024, buf0, 2048, 1024, 2048, nullptr, nullptr, 0);
    // 2) xc = silu(causal_conv(xh) + cb)
    conv_kernel<<<dim3(256, 4), 256, 0, stream>>>(buf0, conv_w, conv_b, buf1);
    // 3) dbc = xc @ W_x^T   M=8192 N=96 K=2048, split-K x4 -> f32 partials
    gemm_bt<0, float><<<dim3(64, 1, 4), 256, 0, stream>>>(
        buf1, 2048, Wxb, 2048, Pbuf, 96, 512, 96, nullptr, nullptr, 786432);
    reduce_dbc<<<dim3(768), 256, 0, stream>>>(Pbuf, dbc);
    // 4) delta = softplus(dt @ W_dt^T + b_dt)   (lda=96, K=64)
    gemm_bt<1, bf16><<<dim3(64, 16), 256, 0, stream>>>(
        dbc, 96, Wdtb, 64, buf0, 2048, 64, 2048, b_dt, nullptr, 0);
    // 5) chunk-parallel scan (NC=32) -> ry (ungated), in place over xc
    scan_p1<<<dim3(8, 4, 32), 256, 0, stream>>>(
        buf0, dbc, A_raw, buf1, Hbuf, Abuf);
    scan_p2<<<dim3(512), 256, 0, stream>>>(Hbuf, Abuf);
    scan_p3<<<dim3(8, 4, 32), 256, 0, stream>>>(
        buf0, dbc, A_raw, Dvec, Hbuf, buf1, buf1);
    // 6) y = ry * silu(x @ W_in[2048:]^T)   (fused z-GEMM + gate)
    cvt_bf16<<<dim3(4096), 256, 0, stream>>>(x, xb2, 1048576);
    cvt_bf16<<<dim3(1024), 256, 0, stream>>>(W_in + (size_t)2048 * 1024, Whi, 262144);
    gemm_bt<2, bf16><<<dim3(64, 16), 256, 0, stream>>>(
        xb2, 1024, Whi, 1024, buf0, 2048, 1024, 2048, nullptr, buf1, 0);
    // 7) out = y @ W_out^T  (f32 store)  M=8192 N=1024 K=2048
    cvt_bf16<<<dim3(1024), 256, 0, stream>>>(W_out, Woutb, 262144);
    gemm_bt<0, float><<<dim3(64, 8), 256, 0, stream>>>(
        buf0, 2048, Woutb, 2048, out, 1024, 2048, 1024, nullptr, nullptr, 0);
}

// Round 8
// 417.171 us; speedup vs baseline: 1.2038x; 1.0235x over previous
//
#include <hip/hip_runtime.h>
#include <hip/hip_bf16.h>

typedef __bf16 bf16;
typedef __bf16 bf16x4 __attribute__((ext_vector_type(4)));
typedef __bf16 bf16x8 __attribute__((ext_vector_type(8)));
typedef float f32x4 __attribute__((ext_vector_type(4)));

__device__ __forceinline__ float fast_exp2(float x) {
#if __has_builtin(__builtin_amdgcn_exp2f)
    return __builtin_amdgcn_exp2f(x);
#else
    return exp2f(x);
#endif
}

// fast natural log via v_log_f32 -- log1pf() lowers to the slow OCML path
// (~260 VALU inst/elem measured in r6's delta-GEMM; fix was -42 us).
__device__ __forceinline__ float fast_log(float x) {
#if __has_builtin(__builtin_amdgcn_logf)
    return __builtin_amdgcn_logf(x) * 0.6931471805599453f;
#else
    return __logf(x);
#endif
}

// async global->LDS, 16B per lane. lds base must be wave-uniform; the HW
// writes lds + lane*16; the GLOBAL address is per-lane. (m97 pattern)
__device__ __forceinline__ void gload16(bf16* lds, const bf16* g) {
    __builtin_amdgcn_global_load_lds(
        (const __attribute__((address_space(1))) void*)g,
        (__attribute__((address_space(3))) void*)lds,
        16, 0, 0);
}

// ---------------------------------------------------------------------------
// f32 -> bf16 vectorized cast (8 elems / thread)
// ---------------------------------------------------------------------------
__device__ __forceinline__ bf16x8 cvt8(const float* p) {
    float4 a = *(const float4*)p;
    float4 b = *(const float4*)(p + 4);
    bf16x8 r;
    r[0] = (bf16)a.x; r[1] = (bf16)a.y; r[2] = (bf16)a.z; r[3] = (bf16)a.w;
    r[4] = (bf16)b.x; r[5] = (bf16)b.y; r[6] = (bf16)b.z; r[7] = (bf16)b.w;
    return r;
}

__global__ __launch_bounds__(256) void cvt_bf16(
    const float* __restrict__ in, bf16* __restrict__ out, int n8)
{
    int i = blockIdx.x * 256 + threadIdx.x;
    if (i < n8)
        *(bf16x8*)(out + (size_t)i * 8) = cvt8(in + (size_t)i * 8);
}

// one merged pass for all start-of-graph conversions (5 launches -> 1):
// x (1048576 x8), W_in lo (262144), W_in hi (262144), W_x (24576), W_dt (16384)
__global__ __launch_bounds__(256) void cvt_all(
    const float* __restrict__ x,  const float* __restrict__ W_in,
    const float* __restrict__ W_x, const float* __restrict__ W_dt,
    bf16* __restrict__ xb, bf16* __restrict__ Wlo, bf16* __restrict__ Whi,
    bf16* __restrict__ Wxb, bf16* __restrict__ Wdtb)
{
    int i = blockIdx.x * 256 + threadIdx.x;
    if (i < 1048576) {
        *(bf16x8*)(xb + (size_t)i * 8) = cvt8(x + (size_t)i * 8);
    } else if (i < 1310720) {
        int j = i - 1048576;
        *(bf16x8*)(Wlo + (size_t)j * 8) = cvt8(W_in + (size_t)j * 8);
    } else if (i < 1572864) {
        int j = i - 1310720;
        *(bf16x8*)(Whi + (size_t)j * 8) = cvt8(W_in + 2097152 + (size_t)j * 8);
    } else if (i < 1597440) {
        int j = i - 1572864;
        *(bf16x8*)(Wxb + (size_t)j * 8) = cvt8(W_x + (size_t)j * 8);
    } else if (i < 1613824) {
        int j = i - 1597440;
        *(bf16x8*)(Wdtb + (size_t)j * 8) = cvt8(W_dt + (size_t)j * 8);
    }
}

// ---------------------------------------------------------------------------
// C[M x N] = A[M x K] * B[N x K]^T   (A,B bf16; f32 accum; TC out)
// m97 structure: 128x128 tile, BK=32, linear LDS [128][32] (64B rows),
// global_load_lds dwordx4 staging, 2-barrier loop, 4 waves (2x2),
// each wave 4x4 of 16x16x32 MFMA.
// EPI==0: plain   EPI==1: softplus(acc + bias_f32[col])
// EPI==2: out = gmul_bf16[row,col] * silu(acc)
// grid.z splits K: block z computes K range [z*K,(z+1)*K) -> C + z*zstride.
// ---------------------------------------------------------------------------
template <int EPI, typename TC>
__global__ __launch_bounds__(256, 2) void gemm_bt(
    const bf16* __restrict__ A, int lda,
    const bf16* __restrict__ B, int ldb,
    TC* __restrict__ C, int ldc,
    int K, int Neff, const float* __restrict__ bias,
    const bf16* __restrict__ gmul, size_t zstride)
{
    __shared__ bf16 As[128 * 32];
    __shared__ bf16 Bs[128 * 32];

    const int tid  = threadIdx.x;
    const int lane = tid & 63;
    const int wave = tid >> 6;
    const int quad = lane >> 4;
    const int l16  = lane & 15;
    const int wm   = (wave >> 1) << 6;
    const int wn   = (wave & 1) << 6;
    const int bm   = blockIdx.x << 7;
    const int bn   = blockIdx.y << 7;
    const int kb   = blockIdx.z * K;

    const int srow = (wave << 4) + (lane >> 2);
    const int scol = (lane & 3) << 3;

    const bf16* Ag0 = A + (size_t)(bm + srow) * lda + kb + scol;
    const bf16* Ag1 = Ag0 + (size_t)lda * 64;
    int br0 = bn + srow;      br0 = br0 < Neff ? br0 : Neff - 1;
    int br1 = bn + srow + 64; br1 = br1 < Neff ? br1 : Neff - 1;
    const bf16* Bg0 = B + (size_t)br0 * ldb + kb + scol;
    const bf16* Bg1 = B + (size_t)br1 * ldb + kb + scol;

    bf16* Asd0 = As + wave * 512;           // wave-uniform LDS bases
    bf16* Asd1 = As + wave * 512 + 2048;
    bf16* Bsd0 = Bs + wave * 512;
    bf16* Bsd1 = Bs + wave * 512 + 2048;

    f32x4 acc[4][4] = {};

    for (int k0 = 0; k0 < K; k0 += 32) {
        if (k0) __syncthreads();            // protect LDS from overwrite
        gload16(Asd0, Ag0 + k0);
        gload16(Asd1, Ag1 + k0);
        gload16(Bsd0, Bg0 + k0);
        gload16(Bsd1, Bg1 + k0);
        __syncthreads();                    // drains vmcnt before barrier

        bf16x8 af[4], bfr[4];
#pragma unroll
        for (int i = 0; i < 4; ++i) {
            af[i]  = *(const bf16x8*)(As + (wm + i * 16 + l16) * 32 + quad * 8);
            bfr[i] = *(const bf16x8*)(Bs + (wn + i * 16 + l16) * 32 + quad * 8);
        }
#pragma unroll
        for (int mi = 0; mi < 4; ++mi)
#pragma unroll
            for (int ni = 0; ni < 4; ++ni)
                acc[mi][ni] = __builtin_amdgcn_mfma_f32_16x16x32_bf16(
                    af[mi], bfr[ni], acc[mi][ni], 0, 0, 0);
    }

    TC* Cz = C + (size_t)blockIdx.z * zstride;

    // C/D layout: row = quad*4 + r, col = l16  (m89-verified)
#pragma unroll
    for (int mi = 0; mi < 4; ++mi) {
        const int row = bm + wm + mi * 16 + quad * 4;
#pragma unroll
        for (int ni = 0; ni < 4; ++ni) {
            const int col = bn + wn + ni * 16 + l16;
            if (col < Neff) {
                float bc = (EPI == 1) ? bias[col] : 0.f;
#pragma unroll
                for (int r = 0; r < 4; ++r) {
                    float v = acc[mi][ni][r];
                    if (EPI == 1) {
                        v += bc;
                        float sp = fast_log(1.f + __expf(v));
                        v = (v > 15.f) ? v : sp;
                    } else if (EPI == 2) {
                        float g = v / (1.f + __expf(-v));   // silu(z)
                        v = (float)gmul[(size_t)(row + r) * ldc + col] * g;
                    }
                    Cz[(size_t)(row + r) * ldc + col] = (TC)v;
                }
            }
        }
    }
}

// ---------------------------------------------------------------------------
// split-K reduce: dbc[i] = bf16(sum_z P[z][i]),  n = 8192*96, 4 splits
// ---------------------------------------------------------------------------
__global__ __launch_bounds__(256) void reduce_dbc(
    const float* __restrict__ P, bf16* __restrict__ dbc)
{
    const size_t i = ((size_t)blockIdx.x * 256 + threadIdx.x) * 4;
    f32x4 s = *(const f32x4*)(P + i);
#pragma unroll
    for (int z = 1; z < 4; ++z) {
        f32x4 p = *(const f32x4*)(P + (size_t)z * 786432 + i);
        s[0] += p[0]; s[1] += p[1]; s[2] += p[2]; s[3] += p[3];
    }
    bf16x4 o;
    o[0] = (bf16)s[0]; o[1] = (bf16)s[1]; o[2] = (bf16)s[2]; o[3] = (bf16)s[3];
    *(bf16x4*)(dbc + i) = o;
}

// ---------------------------------------------------------------------------
// causal depthwise conv (k=4, left pad 3) + bias + SiLU: xh bf16 -> xc bf16
// t-tiled: each thread produces 8 consecutive t for 8 channels.
// ---------------------------------------------------------------------------
__global__ __launch_bounds__(256) void conv_kernel(
    const bf16* __restrict__ xh, const float* __restrict__ cw,
    const float* __restrict__ cb, bf16* __restrict__ xc)
{
    const int t0 = blockIdx.x << 3;          // 0..2040
    const int b  = blockIdx.y;
    const int d  = threadIdx.x * 8;

    float4 wv[8];           // wv[i] = taps 0..3 of channel d+i
#pragma unroll
    for (int i = 0; i < 8; ++i)
        wv[i] = *(const float4*)(cw + (d + i) * 4);

    float4 cb0 = *(const float4*)(cb + d);
    float4 cb1 = *(const float4*)(cb + d + 4);

    float acc[8][8];
#pragma unroll
    for (int k = 0; k < 8; ++k) {
        acc[k][0] = cb0.x; acc[k][1] = cb0.y; acc[k][2] = cb0.z; acc[k][3] = cb0.w;
        acc[k][4] = cb1.x; acc[k][5] = cb1.y; acc[k][6] = cb1.z; acc[k][7] = cb1.w;
    }

    const bf16* base = xh + ((size_t)b * 2048 + t0) * 2048 + d;

#pragma unroll
    for (int r = 0; r < 11; ++r) {
        const int t_in = t0 - 3 + r;
        if (t_in >= 0) {                     // uniform branch
            bf16x8 v = *(const bf16x8*)(base + (size_t)(r - 3) * 2048);
            float vf[8];
#pragma unroll
            for (int i = 0; i < 8; ++i) vf[i] = (float)v[i];
#pragma unroll
            for (int j = 0; j < 4; ++j) {    // tap j multiplies x[t-3+j]
                const int local = r - j;     // output index t0+local
                if (local >= 0 && local < 8) {
#pragma unroll
                    for (int i = 0; i < 8; ++i) {
                        float w = (j == 0) ? wv[i].x : (j == 1) ? wv[i].y
                                : (j == 2) ? wv[i].z : wv[i].w;
                        acc[local][i] += w * vf[i];
                    }
                }
            }
        }
    }

    bf16* ob = xc + ((size_t)b * 2048 + t0) * 2048 + d;
#pragma unroll
    for (int k = 0; k < 8; ++k) {
        bf16x8 o;
#pragma unroll
        for (int i = 0; i < 8; ++i) {
            float s = acc[k][i];
            o[i] = (bf16)(s / (1.f + __expf(-s)));
        }
        *(bf16x8*)(ob + (size_t)k * 2048) = o;
    }
}

// ---------------------------------------------------------------------------
// Chunk-parallel selective scan, NC=64 chunks x TC=32 t.
// thread = (b, c, d); all 16 states n in registers.
// r6->r7 lesson: TLP (more chunks) is the lever that works; source-level
// ILP gets re-sunk by regalloc.  NC=64 -> 2048 blocks -> 8 blocks/CU ->
// 32 waves/CU (100% cap) vs 50% at NC=32.
// Memory: Hbuf is bf16 (16Mi) and Abuf is GONE -- p1 stores only sum(dt)
// (f32, 2Mi); p2 recomputes A_c = exp2(A2*sdt) itself.
// Hbuf layout: (b, c, d, n).  sdt layout: (b, c, d).
// ---------------------------------------------------------------------------
__global__ __launch_bounds__(256, 4) void scan_p1(
    const bf16* __restrict__ delta, const bf16* __restrict__ dbc,
    const float* __restrict__ A_raw, const bf16* __restrict__ xc,
    bf16* __restrict__ Hb, float* __restrict__ sdtb)
{
    const int d = (blockIdx.x << 8) + threadIdx.x;
    const int b = blockIdx.y;
    const int c = blockIdx.z;

    float A2[16];           // A[n] * log2(e)
#pragma unroll
    for (int n = 0; n < 16; ++n)
        A2[n] = -__expf(A_raw[n * 2048 + d]) * 1.44269504f;

    float h[16];
#pragma unroll
    for (int n = 0; n < 16; ++n) h[n] = 0.f;
    float sdt = 0.f;

    const size_t xbase = ((size_t)(b * 2048 + c * 32)) * 2048 + d;
    const bf16* xp = xc + xbase;
    const bf16* dp = delta + xbase;
    const bf16* bp = dbc + ((size_t)(b * 2048 + c * 32)) * 96 + 64;

    bf16 xr = xp[0], dr = dp[0];
    bf16x8 B0 = *(const bf16x8*)(bp);
    bf16x8 B1 = *(const bf16x8*)(bp + 8);

#pragma unroll 4
    for (int t = 0; t < 32; ++t) {
        const float x  = (float)xr;
        const float dt = (float)dr;
        const bf16x8 Bl = B0, Bh = B1;
        if (t < 31) {
            xr = xp[(size_t)(t + 1) * 2048];
            dr = dp[(size_t)(t + 1) * 2048];
            const bf16* nb = bp + (size_t)(t + 1) * 96;
            B0 = *(const bf16x8*)nb;
            B1 = *(const bf16x8*)(nb + 8);
        }
        const float dx = dt * x;
        sdt += dt;
#pragma unroll
        for (int n = 0; n < 8; ++n) {
            float e = fast_exp2(dt * A2[n]);
            h[n] = e * h[n] + (float)Bl[n] * dx;
        }
#pragma unroll
        for (int n = 0; n < 8; ++n) {
            float e = fast_exp2(dt * A2[n + 8]);
            h[n + 8] = e * h[n + 8] + (float)Bh[n] * dx;
        }
    }

    const size_t hbase = (((size_t)b * 64 + c) * 2048 + d) * 16;
    bf16x8 h0, h1;
#pragma unroll
    for (int n = 0; n < 8; ++n) {
        h0[n] = (bf16)h[n];
        h1[n] = (bf16)h[n + 8];
    }
    *(bf16x8*)(Hb + hbase) = h0;
    *(bf16x8*)(Hb + hbase + 8) = h1;
    sdtb[((size_t)b * 64 + c) * 2048 + d] = sdt;
}

// sequential combine over 64 chunks; recomputes A_c = exp2(A2 * sdt_c).
// thread id = b*32768 + d*16 + n  (H reads/writes coalesced).
__global__ __launch_bounds__(256) void scan_p2(
    bf16* __restrict__ Hb, const float* __restrict__ sdtb,
    const float* __restrict__ A_raw)
{
    const int id  = blockIdx.x * 256 + threadIdx.x;
    const int b   = id >> 15;
    const int rem = id & 32767;
    const int d   = rem >> 4;
    const int n   = rem & 15;

    const float A2 = -__expf(A_raw[n * 2048 + d]) * 1.44269504f;
    const size_t hb = (size_t)b * 64 * 32768 + rem;   // + c*32768
    const size_t sb = (size_t)b * 64 * 2048 + d;      // + c*2048

    float ht = (float)Hb[hb];              // H~_0 = H_0 (already stored)
#pragma unroll 4
    for (int c = 1; c < 64; ++c) {
        float Hv = (float)Hb[hb + (size_t)c * 32768];
        float a  = fast_exp2(A2 * sdtb[sb + (size_t)c * 2048]);
        ht = Hv + a * ht;
        Hb[hb + (size_t)c * 32768] = (bf16)ht;
    }
}

__global__ __launch_bounds__(256, 4) void scan_p3(
    const bf16* __restrict__ delta, const bf16* __restrict__ dbc,
    const float* __restrict__ A_raw, const float* __restrict__ Dvec,
    const bf16* __restrict__ Hb, const bf16* xc, bf16* ry)
{
    const int d = (blockIdx.x << 8) + threadIdx.x;
    const int b = blockIdx.y;
    const int c = blockIdx.z;

    float A2[16];
#pragma unroll
    for (int n = 0; n < 16; ++n)
        A2[n] = -__expf(A_raw[n * 2048 + d]) * 1.44269504f;
    const float Dd = Dvec[d];

    float h[16];
    if (c > 0) {
        const bf16* Hp = Hb + (((size_t)b * 64 + (c - 1)) * 2048 + d) * 16;
        bf16x8 v0 = *(const bf16x8*)Hp;
        bf16x8 v1 = *(const bf16x8*)(Hp + 8);
#pragma unroll
        for (int n = 0; n < 8; ++n) {
            h[n]     = (float)v0[n];
            h[n + 8] = (float)v1[n];
        }
    } else {
#pragma unroll
        for (int n = 0; n < 16; ++n) h[n] = 0.f;
    }

    const size_t xbase = ((size_t)(b * 2048 + c * 32)) * 2048 + d;
    const bf16* xp = xc + xbase;
    const bf16* dp = delta + xbase;
    const bf16* bp = dbc + ((size_t)(b * 2048 + c * 32)) * 96 + 64;
    bf16* yp = ry + xbase;

    bf16 xr = xp[0], dr = dp[0];
    bf16x8 B0 = *(const bf16x8*)(bp);
    bf16x8 B1 = *(const bf16x8*)(bp + 8);
    bf16x8 C0 = *(const bf16x8*)(bp + 16);
    bf16x8 C1 = *(const bf16x8*)(bp + 24);

#pragma unroll 4
    for (int t = 0; t < 32; ++t) {
        const float x  = (float)xr;
        const float dt = (float)dr;
        const bf16x8 Bl = B0, Bh = B1, Cl = C0, Ch = C1;
        if (t < 31) {
            xr = xp[(size_t)(t + 1) * 2048];
            dr = dp[(size_t)(t + 1) * 2048];
            const bf16* nb = bp + (size_t)(t + 1) * 96;
            B0 = *(const bf16x8*)nb;
            B1 = *(const bf16x8*)(nb + 8);
            C0 = *(const bf16x8*)(nb + 16);
            C1 = *(const bf16x8*)(nb + 24);
        }
        const float dx = dt * x;
        float y = Dd * x;
#pragma unroll
        for (int n = 0; n < 8; ++n) {
            float e = fast_exp2(dt * A2[n]);
            h[n] = e * h[n] + (float)Bl[n] * dx;
            y += (float)Cl[n] * h[n];
        }
#pragma unroll
        for (int n = 0; n < 8; ++n) {
            float e = fast_exp2(dt * A2[n + 8]);
            h[n + 8] = e * h[n + 8] + (float)Bh[n] * dx;
            y += (float)Ch[n] * h[n + 8];
        }
        yp[(size_t)t * 2048] = (bf16)y;
    }
}

// ---------------------------------------------------------------------------
// launch.  Inputs: f32. Output: f32 (32 MiB).
// ws (>=64 MiB):
//   buf0 @0    (32Mi): xh -> delta -> y            (bf16)
//   buf1 @32Mi (32Mi): W_in_lo_b16 -> xc -> ry -> W_out_b16
// d_out (32 MiB) timeline (NC=64: H bf16 16Mi + sdt 2Mi, no Abuf):
//   @0      dbc bf16 (1.5Mi)          [gemm3..scan_p3]
//   @2Mi    xb_1 (16Mi) [cvt..gemm1] -> Pbuf f32 (12Mi) [gemm3..reduce]
//           -> Hb bf16 (16Mi) [p1..p3] -> xb_2 (16Mi) [cvt..gemm6]
//   @18Mi   sdt f32 (2Mi)             [p1..p2]
//   @20Mi   Whi bf16 (4Mi)            [cvt_all..gemm6]
//   @24Mi   Wxb (384Ki) [..gemm3] | @24.5Mi Wdtb (256Ki) [..gemm4]
// gemm7 writes out over all of d_out (reads only ws).
// ---------------------------------------------------------------------------
extern "C" void kernel_launch(void* const* d_in, const int* in_sizes, int n_in,
                              void* d_out, int out_size, void* d_ws, size_t ws_size,
                              hipStream_t stream)
{
    const float* x      = (const float*)d_in[0];
    const float* W_in   = (const float*)d_in[1];
    const float* conv_w = (const float*)d_in[2];
    const float* conv_b = (const float*)d_in[3];
    const float* W_x    = (const float*)d_in[4];
    const float* W_dt   = (const float*)d_in[5];
    const float* b_dt   = (const float*)d_in[6];
    const float* A_raw  = (const float*)d_in[7];
    const float* Dvec   = (const float*)d_in[8];
    const float* W_out  = (const float*)d_in[9];
    float* out = (float*)d_out;

    char* ws = (char*)d_ws;
    bf16*  buf0   = (bf16*)(ws + 0);           // xh -> delta -> y
    bf16*  buf1   = (bf16*)(ws + 33554432);    // W_in_lo -> xc -> ry -> W_out
    char*  dob    = (char*)d_out;
    bf16*  dbc    = (bf16*)dob;
    bf16*  xb1    = (bf16*)(dob + 2097152);    // x bf16 (16Mi), until gemm1
    float* Pbuf   = (float*)(dob + 2097152);   // gemm3 partials (12Mi)
    bf16*  Hb     = (bf16*)(dob + 2097152);    // scan H bf16 (16Mi, NC=64)
    bf16*  xb2    = (bf16*)(dob + 2097152);    // x bf16 again, for gemm6
    float* sdtb   = (float*)(dob + 18874368);  // 2Mi
    bf16*  Whi    = (bf16*)(dob + 20971520);   // W_in_hi (4Mi)
    bf16*  Wxb    = (bf16*)(dob + 25165824);   // 384Ki
    bf16*  Wdtb   = (bf16*)(dob + 25690112);   // 256Ki
    bf16*  Wlo    = buf1;                       // W_in_lo (4Mi), pre-conv
    bf16*  Woutb  = buf1;                       // W_out (4Mi), post-gemm6

    // 0) merged one-time bf16 conversions (x, W_in lo+hi, W_x, W_dt)
    cvt_all<<<dim3(6304), 256, 0, stream>>>(
        x, W_in, W_x, W_dt, xb1, Wlo, Whi, Wxb, Wdtb);

    // 1) xh = x @ W_in[:2048]^T          M=8192 N=2048 K=1024
    gemm_bt<0, bf16><<<dim3(64, 16), 256, 0, stream>>>(
        xb1, 1024, Wlo, 1024, buf0, 2048, 1024, 2048, nullptr, nullptr, 0);
    // 2) xc = silu(causal_conv(xh) + cb)
    conv_kernel<<<dim3(256, 4), 256, 0, stream>>>(buf0, conv_w, conv_b, buf1);
    // 3) dbc = xc @ W_x^T   M=8192 N=96 K=2048, split-K x4 -> f32 partials
    gemm_bt<0, float><<<dim3(64, 1, 4), 256, 0, stream>>>(
        buf1, 2048, Wxb, 2048, Pbuf, 96, 512, 96, nullptr, nullptr, 786432);
    reduce_dbc<<<dim3(768), 256, 0, stream>>>(Pbuf, dbc);
    // 4) delta = softplus(dt @ W_dt^T + b_dt)   (lda=96, K=64)
    gemm_bt<1, bf16><<<dim3(64, 16), 256, 0, stream>>>(
        dbc, 96, Wdtb, 64, buf0, 2048, 64, 2048, b_dt, nullptr, 0);
    // 5) chunk-parallel scan (NC=64) -> ry (ungated), in place over xc
    scan_p1<<<dim3(8, 4, 64), 256, 0, stream>>>(
        buf0, dbc, A_raw, buf1, Hb, sdtb);
    scan_p2<<<dim3(512), 256, 0, stream>>>(Hb, sdtb, A_raw);
    scan_p3<<<dim3(8, 4, 64), 256, 0, stream>>>(
        buf0, dbc, A_raw, Dvec, Hb, buf1, buf1);
    // 6) y = ry * silu(x @ W_in[2048:]^T)   (fused z-GEMM + gate)
    cvt_bf16<<<dim3(4096), 256, 0, stream>>>(x, xb2, 1048576);
    gemm_bt<2, bf16><<<dim3(64, 16), 256, 0, stream>>>(
        xb2, 1024, Whi, 1024, buf0, 2048, 1024, 2048, nullptr, buf1, 0);
    // 7) out = y @ W_out^T  (f32 store)  M=8192 N=1024 K=2048
    cvt_bf16<<<dim3(1024), 256, 0, stream>>>(W_out, Woutb, 262144);
    gemm_bt<0, float><<<dim3(64, 8), 256, 0, stream>>>(
        buf0, 2048, Woutb, 2048, out, 1024, 2048, 1024, nullptr, nullptr, 0);
}

// Round 9
// 412.497 us; speedup vs baseline: 1.2175x; 1.0113x over previous
//
#include <hip/hip_runtime.h>
#include <hip/hip_bf16.h>

typedef __bf16 bf16;
typedef __bf16 bf16x4 __attribute__((ext_vector_type(4)));
typedef __bf16 bf16x8 __attribute__((ext_vector_type(8)));
typedef float f32x4 __attribute__((ext_vector_type(4)));

__device__ __forceinline__ float fast_exp2(float x) {
#if __has_builtin(__builtin_amdgcn_exp2f)
    return __builtin_amdgcn_exp2f(x);
#else
    return exp2f(x);
#endif
}

// fast natural log via v_log_f32 -- log1pf() lowers to the slow OCML path
// (~260 VALU inst/elem measured in r6's delta-GEMM; fix was -42 us).
__device__ __forceinline__ float fast_log(float x) {
#if __has_builtin(__builtin_amdgcn_logf)
    return __builtin_amdgcn_logf(x) * 0.6931471805599453f;
#else
    return __logf(x);
#endif
}

// async global->LDS, 16B per lane. lds base must be wave-uniform; the HW
// writes lds + lane*16; the GLOBAL address is per-lane. (m97 pattern)
__device__ __forceinline__ void gload16(bf16* lds, const bf16* g) {
    __builtin_amdgcn_global_load_lds(
        (const __attribute__((address_space(1))) void*)g,
        (__attribute__((address_space(3))) void*)lds,
        16, 0, 0);
}

// ---------------------------------------------------------------------------
// f32 -> bf16 vectorized cast (8 elems / thread)
// ---------------------------------------------------------------------------
__device__ __forceinline__ bf16x8 cvt8(const float* p) {
    float4 a = *(const float4*)p;
    float4 b = *(const float4*)(p + 4);
    bf16x8 r;
    r[0] = (bf16)a.x; r[1] = (bf16)a.y; r[2] = (bf16)a.z; r[3] = (bf16)a.w;
    r[4] = (bf16)b.x; r[5] = (bf16)b.y; r[6] = (bf16)b.z; r[7] = (bf16)b.w;
    return r;
}

__global__ __launch_bounds__(256) void cvt_bf16(
    const float* __restrict__ in, bf16* __restrict__ out, int n8)
{
    int i = blockIdx.x * 256 + threadIdx.x;
    if (i < n8)
        *(bf16x8*)(out + (size_t)i * 8) = cvt8(in + (size_t)i * 8);
}

// one merged pass for all start-of-graph conversions (5 launches -> 1):
// x (1048576 x8), W_in lo (262144), W_in hi (262144), W_x (24576), W_dt (16384)
__global__ __launch_bounds__(256) void cvt_all(
    const float* __restrict__ x,  const float* __restrict__ W_in,
    const float* __restrict__ W_x, const float* __restrict__ W_dt,
    bf16* __restrict__ xb, bf16* __restrict__ Wlo, bf16* __restrict__ Whi,
    bf16* __restrict__ Wxb, bf16* __restrict__ Wdtb)
{
    int i = blockIdx.x * 256 + threadIdx.x;
    if (i < 1048576) {
        *(bf16x8*)(xb + (size_t)i * 8) = cvt8(x + (size_t)i * 8);
    } else if (i < 1310720) {
        int j = i - 1048576;
        *(bf16x8*)(Wlo + (size_t)j * 8) = cvt8(W_in + (size_t)j * 8);
    } else if (i < 1572864) {
        int j = i - 1310720;
        *(bf16x8*)(Whi + (size_t)j * 8) = cvt8(W_in + 2097152 + (size_t)j * 8);
    } else if (i < 1597440) {
        int j = i - 1572864;
        *(bf16x8*)(Wxb + (size_t)j * 8) = cvt8(W_x + (size_t)j * 8);
    } else if (i < 1613824) {
        int j = i - 1597440;
        *(bf16x8*)(Wdtb + (size_t)j * 8) = cvt8(W_dt + (size_t)j * 8);
    }
}

// ---------------------------------------------------------------------------
// C[M x N] = A[M x K] * B[N x K]^T   (A,B bf16; f32 accum; TC out)
// m97 structure upgraded to BK=64: four [128][32] LDS sub-buffers (each the
// m97-verified 64B-row geometry, so ds_read bank behavior is unchanged),
// 8 global_load_lds dwordx4 per thread per K-step, 2-barrier loop -- HALF
// the vmcnt(0) barrier drains of BK=32 at the same 32 KB LDS (5 blocks/CU,
// occupancy unchanged).  4 waves (2x2), wave = 4x4x2kk of 16x16x32 MFMA.
// EPI==0: plain   EPI==1: softplus(acc + bias_f32[col])
// EPI==2: out = gmul_bf16[row,col] * silu(acc)
// grid.z splits K: block z computes K range [z*K,(z+1)*K) -> C + z*zstride.
// Requires K % 64 == 0 (all call sites: 1024/2048/512/64).
// ---------------------------------------------------------------------------
template <int EPI, typename TC>
__global__ __launch_bounds__(256, 2) void gemm_bt(
    const bf16* __restrict__ A, int lda,
    const bf16* __restrict__ B, int ldb,
    TC* __restrict__ C, int ldc,
    int K, int Neff, const float* __restrict__ bias,
    const bf16* __restrict__ gmul, size_t zstride)
{
    __shared__ bf16 As0[128 * 32];
    __shared__ bf16 As1[128 * 32];
    __shared__ bf16 Bs0[128 * 32];
    __shared__ bf16 Bs1[128 * 32];

    const int tid  = threadIdx.x;
    const int lane = tid & 63;
    const int wave = tid >> 6;
    const int quad = lane >> 4;
    const int l16  = lane & 15;
    const int wm   = (wave >> 1) << 6;
    const int wn   = (wave & 1) << 6;
    const int bm   = blockIdx.x << 7;
    const int bn   = blockIdx.y << 7;
    const int kb   = blockIdx.z * K;

    // staging map: wave w covers LDS rows [w*16, +16) of each 64-row half
    // lane l -> row +(l>>2), col (l&3)*8   (lds dest = uniform base + l*16B)
    const int srow = (wave << 4) + (lane >> 2);
    const int scol = (lane & 3) << 3;

    const bf16* Ag0 = A + (size_t)(bm + srow) * lda + kb + scol;
    const bf16* Ag1 = Ag0 + (size_t)lda * 64;
    int br0 = bn + srow;      br0 = br0 < Neff ? br0 : Neff - 1;
    int br1 = bn + srow + 64; br1 = br1 < Neff ? br1 : Neff - 1;
    const bf16* Bg0 = B + (size_t)br0 * ldb + kb + scol;
    const bf16* Bg1 = B + (size_t)br1 * ldb + kb + scol;

    const int wofs = wave * 512;            // wave-uniform LDS base offset

    f32x4 acc[4][4] = {};

    for (int k0 = 0; k0 < K; k0 += 64) {
        if (k0) __syncthreads();            // protect LDS from overwrite
        // kk=0 slice (cols k0..k0+31)
        gload16(As0 + wofs,        Ag0 + k0);
        gload16(As0 + 2048 + wofs, Ag1 + k0);
        gload16(Bs0 + wofs,        Bg0 + k0);
        gload16(Bs0 + 2048 + wofs, Bg1 + k0);
        // kk=1 slice (cols k0+32..k0+63)
        gload16(As1 + wofs,        Ag0 + k0 + 32);
        gload16(As1 + 2048 + wofs, Ag1 + k0 + 32);
        gload16(Bs1 + wofs,        Bg0 + k0 + 32);
        gload16(Bs1 + 2048 + wofs, Bg1 + k0 + 32);
        __syncthreads();                    // drains vmcnt before barrier

#pragma unroll
        for (int kk = 0; kk < 2; ++kk) {
            const bf16* Ak = kk ? As1 : As0;
            const bf16* Bk = kk ? Bs1 : Bs0;
            bf16x8 af[4], bfr[4];
#pragma unroll
            for (int i = 0; i < 4; ++i) {
                af[i]  = *(const bf16x8*)(Ak + (wm + i * 16 + l16) * 32 + quad * 8);
                bfr[i] = *(const bf16x8*)(Bk + (wn + i * 16 + l16) * 32 + quad * 8);
            }
#pragma unroll
            for (int mi = 0; mi < 4; ++mi)
#pragma unroll
                for (int ni = 0; ni < 4; ++ni)
                    acc[mi][ni] = __builtin_amdgcn_mfma_f32_16x16x32_bf16(
                        af[mi], bfr[ni], acc[mi][ni], 0, 0, 0);
        }
    }

    TC* Cz = C + (size_t)blockIdx.z * zstride;

    // C/D layout: row = quad*4 + r, col = l16  (m89-verified)
#pragma unroll
    for (int mi = 0; mi < 4; ++mi) {
        const int row = bm + wm + mi * 16 + quad * 4;
#pragma unroll
        for (int ni = 0; ni < 4; ++ni) {
            const int col = bn + wn + ni * 16 + l16;
            if (col < Neff) {
                float bc = (EPI == 1) ? bias[col] : 0.f;
#pragma unroll
                for (int r = 0; r < 4; ++r) {
                    float v = acc[mi][ni][r];
                    if (EPI == 1) {
                        v += bc;
                        float sp = fast_log(1.f + __expf(v));
                        v = (v > 15.f) ? v : sp;
                    } else if (EPI == 2) {
                        float g = v / (1.f + __expf(-v));   // silu(z)
                        v = (float)gmul[(size_t)(row + r) * ldc + col] * g;
                    }
                    Cz[(size_t)(row + r) * ldc + col] = (TC)v;
                }
            }
        }
    }
}

// ---------------------------------------------------------------------------
// split-K reduce: dbc[i] = bf16(sum_z P[z][i]),  n = 8192*96, 4 splits
// ---------------------------------------------------------------------------
__global__ __launch_bounds__(256) void reduce_dbc(
    const float* __restrict__ P, bf16* __restrict__ dbc)
{
    const size_t i = ((size_t)blockIdx.x * 256 + threadIdx.x) * 4;
    f32x4 s = *(const f32x4*)(P + i);
#pragma unroll
    for (int z = 1; z < 4; ++z) {
        f32x4 p = *(const f32x4*)(P + (size_t)z * 786432 + i);
        s[0] += p[0]; s[1] += p[1]; s[2] += p[2]; s[3] += p[3];
    }
    bf16x4 o;
    o[0] = (bf16)s[0]; o[1] = (bf16)s[1]; o[2] = (bf16)s[2]; o[3] = (bf16)s[3];
    *(bf16x4*)(dbc + i) = o;
}

// ---------------------------------------------------------------------------
// causal depthwise conv (k=4, left pad 3) + bias + SiLU: xh bf16 -> xc bf16
// t-tiled: each thread produces 8 consecutive t for 8 channels.
// ---------------------------------------------------------------------------
__global__ __launch_bounds__(256) void conv_kernel(
    const bf16* __restrict__ xh, const float* __restrict__ cw,
    const float* __restrict__ cb, bf16* __restrict__ xc)
{
    const int t0 = blockIdx.x << 3;          // 0..2040
    const int b  = blockIdx.y;
    const int d  = threadIdx.x * 8;

    float4 wv[8];           // wv[i] = taps 0..3 of channel d+i
#pragma unroll
    for (int i = 0; i < 8; ++i)
        wv[i] = *(const float4*)(cw + (d + i) * 4);

    float4 cb0 = *(const float4*)(cb + d);
    float4 cb1 = *(const float4*)(cb + d + 4);

    float acc[8][8];
#pragma unroll
    for (int k = 0; k < 8; ++k) {
        acc[k][0] = cb0.x; acc[k][1] = cb0.y; acc[k][2] = cb0.z; acc[k][3] = cb0.w;
        acc[k][4] = cb1.x; acc[k][5] = cb1.y; acc[k][6] = cb1.z; acc[k][7] = cb1.w;
    }

    const bf16* base = xh + ((size_t)b * 2048 + t0) * 2048 + d;

#pragma unroll
    for (int r = 0; r < 11; ++r) {
        const int t_in = t0 - 3 + r;
        if (t_in >= 0) {                     // uniform branch
            bf16x8 v = *(const bf16x8*)(base + (size_t)(r - 3) * 2048);
            float vf[8];
#pragma unroll
            for (int i = 0; i < 8; ++i) vf[i] = (float)v[i];
#pragma unroll
            for (int j = 0; j < 4; ++j) {    // tap j multiplies x[t-3+j]
                const int local = r - j;     // output index t0+local
                if (local >= 0 && local < 8) {
#pragma unroll
                    for (int i = 0; i < 8; ++i) {
                        float w = (j == 0) ? wv[i].x : (j == 1) ? wv[i].y
                                : (j == 2) ? wv[i].z : wv[i].w;
                        acc[local][i] += w * vf[i];
                    }
                }
            }
        }
    }

    bf16* ob = xc + ((size_t)b * 2048 + t0) * 2048 + d;
#pragma unroll
    for (int k = 0; k < 8; ++k) {
        bf16x8 o;
#pragma unroll
        for (int i = 0; i < 8; ++i) {
            float s = acc[k][i];
            o[i] = (bf16)(s / (1.f + __expf(-s)));
        }
        *(bf16x8*)(ob + (size_t)k * 2048) = o;
    }
}

// ---------------------------------------------------------------------------
// Chunk-parallel selective scan, NC=64 chunks x TC=32 t.
// thread = (b, c, d); all 16 states n in registers.  NC=64 -> 2048 blocks
// -> 8 blocks/CU -> 32 waves/CU cap.  (TLP is the lever that works; r4/r5
// showed source-level ILP pipelines get re-sunk by regalloc.)
// p3 measured r8: 55.5us @ 75% VALUBusy -- near the 16-exp/elem trans floor.
// Hb layout: (b, c, d, n) bf16.  sdt: (b, c, d) f32; p2 recomputes A_c.
// ---------------------------------------------------------------------------
__global__ __launch_bounds__(256, 4) void scan_p1(
    const bf16* __restrict__ delta, const bf16* __restrict__ dbc,
    const float* __restrict__ A_raw, const bf16* __restrict__ xc,
    bf16* __restrict__ Hb, float* __restrict__ sdtb)
{
    const int d = (blockIdx.x << 8) + threadIdx.x;
    const int b = blockIdx.y;
    const int c = blockIdx.z;

    float A2[16];           // A[n] * log2(e)
#pragma unroll
    for (int n = 0; n < 16; ++n)
        A2[n] = -__expf(A_raw[n * 2048 + d]) * 1.44269504f;

    float h[16];
#pragma unroll
    for (int n = 0; n < 16; ++n) h[n] = 0.f;
    float sdt = 0.f;

    const size_t xbase = ((size_t)(b * 2048 + c * 32)) * 2048 + d;
    const bf16* xp = xc + xbase;
    const bf16* dp = delta + xbase;
    const bf16* bp = dbc + ((size_t)(b * 2048 + c * 32)) * 96 + 64;

    bf16 xr = xp[0], dr = dp[0];
    bf16x8 B0 = *(const bf16x8*)(bp);
    bf16x8 B1 = *(const bf16x8*)(bp + 8);

#pragma unroll 4
    for (int t = 0; t < 32; ++t) {
        const float x  = (float)xr;
        const float dt = (float)dr;
        const bf16x8 Bl = B0, Bh = B1;
        if (t < 31) {
            xr = xp[(size_t)(t + 1) * 2048];
            dr = dp[(size_t)(t + 1) * 2048];
            const bf16* nb = bp + (size_t)(t + 1) * 96;
            B0 = *(const bf16x8*)nb;
            B1 = *(const bf16x8*)(nb + 8);
        }
        const float dx = dt * x;
        sdt += dt;
#pragma unroll
        for (int n = 0; n < 8; ++n) {
            float e = fast_exp2(dt * A2[n]);
            h[n] = e * h[n] + (float)Bl[n] * dx;
        }
#pragma unroll
        for (int n = 0; n < 8; ++n) {
            float e = fast_exp2(dt * A2[n + 8]);
            h[n + 8] = e * h[n + 8] + (float)Bh[n] * dx;
        }
    }

    const size_t hbase = (((size_t)b * 64 + c) * 2048 + d) * 16;
    bf16x8 h0, h1;
#pragma unroll
    for (int n = 0; n < 8; ++n) {
        h0[n] = (bf16)h[n];
        h1[n] = (bf16)h[n + 8];
    }
    *(bf16x8*)(Hb + hbase) = h0;
    *(bf16x8*)(Hb + hbase + 8) = h1;
    sdtb[((size_t)b * 64 + c) * 2048 + d] = sdt;
}

// sequential combine over 64 chunks; recomputes A_c = exp2(A2 * sdt_c).
// thread id = b*32768 + d*16 + n  (H reads/writes coalesced).
__global__ __launch_bounds__(256) void scan_p2(
    bf16* __restrict__ Hb, const float* __restrict__ sdtb,
    const float* __restrict__ A_raw)
{
    const int id  = blockIdx.x * 256 + threadIdx.x;
    const int b   = id >> 15;
    const int rem = id & 32767;
    const int d   = rem >> 4;
    const int n   = rem & 15;

    const float A2 = -__expf(A_raw[n * 2048 + d]) * 1.44269504f;
    const size_t hb = (size_t)b * 64 * 32768 + rem;   // + c*32768
    const size_t sb = (size_t)b * 64 * 2048 + d;      // + c*2048

    float ht = (float)Hb[hb];              // H~_0 = H_0 (already stored)
#pragma unroll 4
    for (int c = 1; c < 64; ++c) {
        float Hv = (float)Hb[hb + (size_t)c * 32768];
        float a  = fast_exp2(A2 * sdtb[sb + (size_t)c * 2048]);
        ht = Hv + a * ht;
        Hb[hb + (size_t)c * 32768] = (bf16)ht;
    }
}

__global__ __launch_bounds__(256, 4) void scan_p3(
    const bf16* __restrict__ delta, const bf16* __restrict__ dbc,
    const float* __restrict__ A_raw, const float* __restrict__ Dvec,
    const bf16* __restrict__ Hb, const bf16* xc, bf16* ry)
{
    const int d = (blockIdx.x << 8) + threadIdx.x;
    const int b = blockIdx.y;
    const int c = blockIdx.z;

    float A2[16];
#pragma unroll
    for (int n = 0; n < 16; ++n)
        A2[n] = -__expf(A_raw[n * 2048 + d]) * 1.44269504f;
    const float Dd = Dvec[d];

    float h[16];
    if (c > 0) {
        const bf16* Hp = Hb + (((size_t)b * 64 + (c - 1)) * 2048 + d) * 16;
        bf16x8 v0 = *(const bf16x8*)Hp;
        bf16x8 v1 = *(const bf16x8*)(Hp + 8);
#pragma unroll
        for (int n = 0; n < 8; ++n) {
            h[n]     = (float)v0[n];
            h[n + 8] = (float)v1[n];
        }
    } else {
#pragma unroll
        for (int n = 0; n < 16; ++n) h[n] = 0.f;
    }

    const size_t xbase = ((size_t)(b * 2048 + c * 32)) * 2048 + d;
    const bf16* xp = xc + xbase;
    const bf16* dp = delta + xbase;
    const bf16* bp = dbc + ((size_t)(b * 2048 + c * 32)) * 96 + 64;
    bf16* yp = ry + xbase;

    bf16 xr = xp[0], dr = dp[0];
    bf16x8 B0 = *(const bf16x8*)(bp);
    bf16x8 B1 = *(const bf16x8*)(bp + 8);
    bf16x8 C0 = *(const bf16x8*)(bp + 16);
    bf16x8 C1 = *(const bf16x8*)(bp + 24);

#pragma unroll 4
    for (int t = 0; t < 32; ++t) {
        const float x  = (float)xr;
        const float dt = (float)dr;
        const bf16x8 Bl = B0, Bh = B1, Cl = C0, Ch = C1;
        if (t < 31) {
            xr = xp[(size_t)(t + 1) * 2048];
            dr = dp[(size_t)(t + 1) * 2048];
            const bf16* nb = bp + (size_t)(t + 1) * 96;
            B0 = *(const bf16x8*)nb;
            B1 = *(const bf16x8*)(nb + 8);
            C0 = *(const bf16x8*)(nb + 16);
            C1 = *(const bf16x8*)(nb + 24);
        }
        const float dx = dt * x;
        float y = Dd * x;
#pragma unroll
        for (int n = 0; n < 8; ++n) {
            float e = fast_exp2(dt * A2[n]);
            h[n] = e * h[n] + (float)Bl[n] * dx;
            y += (float)Cl[n] * h[n];
        }
#pragma unroll
        for (int n = 0; n < 8; ++n) {
            float e = fast_exp2(dt * A2[n + 8]);
            h[n + 8] = e * h[n + 8] + (float)Bh[n] * dx;
            y += (float)Ch[n] * h[n + 8];
        }
        yp[(size_t)t * 2048] = (bf16)y;
    }
}

// ---------------------------------------------------------------------------
// launch.  Inputs: f32. Output: f32 (32 MiB).
// ws (>=64 MiB):
//   buf0 @0    (32Mi): xh -> delta -> y            (bf16)
//   buf1 @32Mi (32Mi): W_in_lo_b16 -> xc -> ry -> W_out_b16
// d_out (32 MiB) timeline (NC=64: H bf16 16Mi + sdt 2Mi, no Abuf):
//   @0      dbc bf16 (1.5Mi)          [gemm3..scan_p3]
//   @2Mi    xb_1 (16Mi) [cvt..gemm1] -> Pbuf f32 (12Mi) [gemm3..reduce]
//           -> Hb bf16 (16Mi) [p1..p3] -> xb_2 (16Mi) [cvt..gemm6]
//   @18Mi   sdt f32 (2Mi)             [p1..p2]
//   @20Mi   Whi bf16 (4Mi)            [cvt_all..gemm6]
//   @24Mi   Wxb (384Ki) [..gemm3] | @24.5Mi Wdtb (256Ki) [..gemm4]
// gemm7 writes out over all of d_out (reads only ws).
// ---------------------------------------------------------------------------
extern "C" void kernel_launch(void* const* d_in, const int* in_sizes, int n_in,
                              void* d_out, int out_size, void* d_ws, size_t ws_size,
                              hipStream_t stream)
{
    const float* x      = (const float*)d_in[0];
    const float* W_in   = (const float*)d_in[1];
    const float* conv_w = (const float*)d_in[2];
    const float* conv_b = (const float*)d_in[3];
    const float* W_x    = (const float*)d_in[4];
    const float* W_dt   = (const float*)d_in[5];
    const float* b_dt   = (const float*)d_in[6];
    const float* A_raw  = (const float*)d_in[7];
    const float* Dvec   = (const float*)d_in[8];
    const float* W_out  = (const float*)d_in[9];
    float* out = (float*)d_out;

    char* ws = (char*)d_ws;
    bf16*  buf0   = (bf16*)(ws + 0);           // xh -> delta -> y
    bf16*  buf1   = (bf16*)(ws + 33554432);    // W_in_lo -> xc -> ry -> W_out
    char*  dob    = (char*)d_out;
    bf16*  dbc    = (bf16*)dob;
    bf16*  xb1    = (bf16*)(dob + 2097152);    // x bf16 (16Mi), until gemm1
    float* Pbuf   = (float*)(dob + 2097152);   // gemm3 partials (12Mi)
    bf16*  Hb     = (bf16*)(dob + 2097152);    // scan H bf16 (16Mi, NC=64)
    bf16*  xb2    = (bf16*)(dob + 2097152);    // x bf16 again, for gemm6
    float* sdtb   = (float*)(dob + 18874368);  // 2Mi
    bf16*  Whi    = (bf16*)(dob + 20971520);   // W_in_hi (4Mi)
    bf16*  Wxb    = (bf16*)(dob + 25165824);   // 384Ki
    bf16*  Wdtb   = (bf16*)(dob + 25690112);   // 256Ki
    bf16*  Wlo    = buf1;                       // W_in_lo (4Mi), pre-conv
    bf16*  Woutb  = buf1;                       // W_out (4Mi), post-gemm6

    // 0) merged one-time bf16 conversions (x, W_in lo+hi, W_x, W_dt)
    cvt_all<<<dim3(6304), 256, 0, stream>>>(
        x, W_in, W_x, W_dt, xb1, Wlo, Whi, Wxb, Wdtb);

    // 1) xh = x @ W_in[:2048]^T          M=8192 N=2048 K=1024
    gemm_bt<0, bf16><<<dim3(64, 16), 256, 0, stream>>>(
        xb1, 1024, Wlo, 1024, buf0, 2048, 1024, 2048, nullptr, nullptr, 0);
    // 2) xc = silu(causal_conv(xh) + cb)
    conv_kernel<<<dim3(256, 4), 256, 0, stream>>>(buf0, conv_w, conv_b, buf1);
    // 3) dbc = xc @ W_x^T   M=8192 N=96 K=2048, split-K x4 -> f32 partials
    gemm_bt<0, float><<<dim3(64, 1, 4), 256, 0, stream>>>(
        buf1, 2048, Wxb, 2048, Pbuf, 96, 512, 96, nullptr, nullptr, 786432);
    reduce_dbc<<<dim3(768), 256, 0, stream>>>(Pbuf, dbc);
    // 4) delta = softplus(dt @ W_dt^T + b_dt)   (lda=96, K=64)
    gemm_bt<1, bf16><<<dim3(64, 16), 256, 0, stream>>>(
        dbc, 96, Wdtb, 64, buf0, 2048, 64, 2048, b_dt, nullptr, 0);
    // 5) chunk-parallel scan (NC=64) -> ry (ungated), in place over xc
    scan_p1<<<dim3(8, 4, 64), 256, 0, stream>>>(
        buf0, dbc, A_raw, buf1, Hb, sdtb);
    scan_p2<<<dim3(512), 256, 0, stream>>>(Hb, sdtb, A_raw);
    scan_p3<<<dim3(8, 4, 64), 256, 0, stream>>>(
        buf0, dbc, A_raw, Dvec, Hb, buf1, buf1);
    // 6) y = ry * silu(x @ W_in[2048:]^T)   (fused z-GEMM + gate)
    cvt_bf16<<<dim3(4096), 256, 0, stream>>>(x, xb2, 1048576);
    gemm_bt<2, bf16><<<dim3(64, 16), 256, 0, stream>>>(
        xb2, 1024, Whi, 1024, buf0, 2048, 1024, 2048, nullptr, buf1, 0);
    // 7) out = y @ W_out^T  (f32 store)  M=8192 N=1024 K=2048
    cvt_bf16<<<dim3(1024), 256, 0, stream>>>(W_out, Woutb, 262144);
    gemm_bt<0, float><<<dim3(64, 8), 256, 0, stream>>>(
        buf0, 2048, Woutb, 2048, out, 1024, 2048, 1024, nullptr, nullptr, 0);
}